// Round 9
// baseline (458.331 us; speedup 1.0000x reference)
//
#include <hip/hip_runtime.h>

#define NN 4096
#define SLOPE 0.2f

typedef float f4_t __attribute__((ext_vector_type(4)));
typedef __bf16 bf8v __attribute__((ext_vector_type(8)));
typedef float f32x16 __attribute__((ext_vector_type(16)));

// ---- workspace layout (float offsets unless noted) ----
#define V_OFF     0                        // v1i,v2i,v1s,v2s : 4*128
#define C_OFF     512                      // 4 score constants
#define BT_OFF    516                      // b_total[128]
#define S_OFF     1024                     // s1i,s2i,s1s,s2s : 4*4096
#define HXI_OFF   32768                    // Ld@x   [4096,128] fp32
#define HXS_OFF   (HXI_OFF + NN*128)       // Lu@x
#define UI_OFF    (HXS_OFF + NN*128)       // U_irr bf16 hi/lo fragment buffers
#define US_OFF    (UI_OFF + NN*128)        // U_sol bf16 hi/lo fragment buffers
#define XWH_OFF   (US_OFF + NN*128)        // xwhT hi/lo bf16 fragment buffers
#define OI_OFF    (XWH_OFF + NN*128)       // O_irr fp32
#define OS_OFF    (OI_OFF + NN*128)        // O_sol fp32
#define ZP_OFF    (OS_OFF + NN*128)        // P@xWh split-K partials: 8 * [4096,128]
#define WS_FLOATS (ZP_OFF + 8*NN*128)
#define XF_BYTE_OFF ((size_t)WS_FLOATS * 4)   // x fragment hi/lo buffers (2 MB)

// Pad map for fp32 LDS GEMM tiles (4-way -> 2-way, free per m136).
#define XI(c)   ((c) + (((c) >> 5) << 2))   // [0,128) -> [0,140)

// XCD-aware (block,branch) mapping: blockIdx%8 = XCD; bit 2 selects branch.
#define BMAP_BR(bid)    (((bid) >> 2) & 1)
#define BMAP_RBLK(bid)  ((((bid) >> 3) << 2) | ((bid) & 3))

// MFMA-fragment layout (B operand, 32x32x16 bf16; verified r5-r8):
#define FRAG(c, k) ((size_t)((k) >> 4) * 2048 + (size_t)((c) >> 5) * 512 \
                    + (size_t)((((c) & 31) + 32 * (((k) >> 3) & 1)) * 8 + ((k) & 7)))

// bf16 round-to-nearest-even helpers
__device__ __forceinline__ unsigned short f2bf(float x) {
  unsigned u = __float_as_uint(x);
  return (unsigned short)((u + 0x7FFFu + ((u >> 16) & 1u)) >> 16);
}
__device__ __forceinline__ float bf2f(unsigned short h) {
  return __uint_as_float(((unsigned)h) << 16);
}
union BFU { unsigned short u[8]; bf8v v; };

// ---------------------------------------------------------------------------
// Prep: v-vectors so s1[i] = x[i,:]·v + c, b_total.
__global__ __launch_bounds__(128) void k_prep(
    const float* __restrict__ Wi_w, const float* __restrict__ Wi_b,
    const float* __restrict__ Ws_w, const float* __restrict__ Ws_b,
    const float* __restrict__ Wh_b, const float* __restrict__ att_irr,
    const float* __restrict__ att_sol, float* __restrict__ ws) {
  const int t = threadIdx.x;
  float v1i = 0.f, v2i = 0.f, v1s = 0.f, v2s = 0.f;
  for (int j = 0; j < 2; ++j) {
    for (int o = 0; o < 128; ++o) {
      const float wi = Wi_w[j*16384 + t*128 + o];
      const float wv = Ws_w[j*16384 + t*128 + o];
      v1i += wi * att_irr[j*128 + o];
      v2i += wi * att_irr[256 + j*128 + o];
      v1s += wv * att_sol[j*128 + o];
      v2s += wv * att_sol[256 + j*128 + o];
    }
  }
  ws[V_OFF + t]       = v1i;
  ws[V_OFF + 128 + t] = v2i;
  ws[V_OFF + 256 + t] = v1s;
  ws[V_OFF + 384 + t] = v2s;
  ws[BT_OFF + t] = Wi_b[t] + Wi_b[128 + t] + Ws_b[t] + Ws_b[128 + t] + Wh_b[t];
  if (t < 4) {
    const float* bb = (t < 2) ? Wi_b : Ws_b;
    const float* aa = ((t < 2) ? att_irr : att_sol) + ((t & 1) ? 256 : 0);
    float c = 0.f;
    for (int k = 0; k < 256; ++k) c += bb[k] * aa[k];
    ws[C_OFF + t] = c;
  }
}

// ---------------------------------------------------------------------------
// Fused pre-pass: blocks 0..127 compute xWh = x@Wh -> bf16 hi/lo fragments;
// blocks 128..1151: scores + x -> bf16 hi/lo fragments (feeds k_hxmm).
__global__ __launch_bounds__(256) void k_pre2(
    const float* __restrict__ x, const float* __restrict__ Wh_w,
    float* __restrict__ ws, unsigned short* __restrict__ xth,
    unsigned short* __restrict__ xtl, unsigned short* __restrict__ xfh,
    unsigned short* __restrict__ xfl) {
  __shared__ __align__(16) float At[32][33];
  __shared__ __align__(16) float Wt[32][144];
  const int t = threadIdx.x;

  if (blockIdx.x < 128) {
    const int rb = blockIdx.x;
    const int rg = t >> 4, cg = t & 15;
    const int r0 = rb * 32;
    float acc[2][8];
    #pragma unroll
    for (int i = 0; i < 2; ++i)
      #pragma unroll
      for (int j = 0; j < 8; ++j) acc[i][j] = 0.f;
    for (int k0 = 0; k0 < 128; k0 += 32) {
      __syncthreads();
      {
        const int row = t >> 3, kq = t & 7;
        const float4 av = *(const float4*)&x[(r0 + row)*128 + k0 + kq*4];
        At[row][kq*4+0] = av.x; At[row][kq*4+1] = av.y;
        At[row][kq*4+2] = av.z; At[row][kq*4+3] = av.w;
      }
      #pragma unroll
      for (int l = 0; l < 4; ++l) {
        const int idx = t + l*256;
        const int kr = idx >> 5, c4 = idx & 31;
        const float4 wv = *(const float4*)&Wh_w[(k0 + kr)*128 + c4*4];
        *(float4*)&Wt[kr][XI(c4*4)] = wv;
      }
      __syncthreads();
      #pragma unroll
      for (int k = 0; k < 32; ++k) {
        const float a0 = At[rg*2 + 0][k];
        const float a1 = At[rg*2 + 1][k];
        const float4 b0 = *(const float4*)&Wt[k][XI(cg*8)];
        const float4 b1 = *(const float4*)&Wt[k][XI(cg*8 + 4)];
        acc[0][0] += a0*b0.x; acc[0][1] += a0*b0.y; acc[0][2] += a0*b0.z; acc[0][3] += a0*b0.w;
        acc[0][4] += a0*b1.x; acc[0][5] += a0*b1.y; acc[0][6] += a0*b1.z; acc[0][7] += a0*b1.w;
        acc[1][0] += a1*b0.x; acc[1][1] += a1*b0.y; acc[1][2] += a1*b0.z; acc[1][3] += a1*b0.w;
        acc[1][4] += a1*b1.x; acc[1][5] += a1*b1.y; acc[1][6] += a1*b1.z; acc[1][7] += a1*b1.w;
      }
    }
    #pragma unroll
    for (int i = 0; i < 2; ++i) {
      const int r = r0 + rg*2 + i;       // r = k-index of pgemm
      #pragma unroll
      for (int j = 0; j < 8; ++j) {
        const int c = cg*8 + j;
        const float val = acc[i][j];
        const unsigned short h = f2bf(val);
        const unsigned short l = f2bf(val - bf2f(h));
        const size_t fa = FRAG(c, r);
        xth[fa] = h;
        xtl[fa] = l;
      }
    }
  } else {
    const int wave = t >> 6, lane = t & 63;
    const int row = (blockIdx.x - 128) * 4 + wave;
    const float* v = ws + V_OFF;
    const float x0 = x[row*128 + lane];
    const float x1 = x[row*128 + 64 + lane];
    {
      const unsigned short h0 = f2bf(x0);
      const unsigned short l0 = f2bf(x0 - bf2f(h0));
      const size_t fa0 = FRAG(lane, row);
      xfh[fa0] = h0; xfl[fa0] = l0;
      const unsigned short h1 = f2bf(x1);
      const unsigned short l1 = f2bf(x1 - bf2f(h1));
      const size_t fa1 = FRAG(lane + 64, row);
      xfh[fa1] = h1; xfl[fa1] = l1;
    }
    float p0 = x0 * v[lane]       + x1 * v[64 + lane];
    float p1 = x0 * v[128 + lane] + x1 * v[192 + lane];
    float p2 = x0 * v[256 + lane] + x1 * v[320 + lane];
    float p3 = x0 * v[384 + lane] + x1 * v[448 + lane];
    #pragma unroll
    for (int off = 32; off; off >>= 1) {
      p0 += __shfl_down(p0, off);
      p1 += __shfl_down(p1, off);
      p2 += __shfl_down(p2, off);
      p3 += __shfl_down(p3, off);
    }
    if (lane == 0) {
      ws[S_OFF + row]          = p0 + ws[C_OFF + 0];
      ws[S_OFF + NN + row]     = p1 + ws[C_OFF + 1];
      ws[S_OFF + 2*NN + row]   = p2 + ws[C_OFF + 2];
      ws[S_OFF + 3*NN + row]   = p3 + ws[C_OFF + 3];
    }
  }
}

// ---------------------------------------------------------------------------
// Dense Hx = L@x via MFMA, DEPTH-4 A-PREFETCH (fully unrolled, static idx).
// 512 threads = 8 waves x 512-wide K-chunks; BM=32; grid 256 (1/CU).
__global__ __launch_bounds__(512) void k_hxmm(
    const float* __restrict__ Ld, const float* __restrict__ Lu,
    const unsigned short* __restrict__ xfh, const unsigned short* __restrict__ xfl,
    float* __restrict__ ws) {
  const int bid = blockIdx.x;
  const int br  = BMAP_BR(bid);
  const int rblk = BMAP_RBLK(bid);
  const int t = threadIdx.x;
  const int w = t >> 6, lane = t & 63;
  const int la = lane & 31;
  const int koff = (lane >> 5) * 8;
  const int r0 = rblk * 32;
  const int kb = w * 512;
  const float* __restrict__ L = br ? Lu : Ld;
  float* __restrict__ Hx = ws + (br ? HXS_OFF : HXI_OFF);

  f32x16 acc[4];
  #pragma unroll
  for (int n = 0; n < 4; ++n)
    #pragma unroll
    for (int e = 0; e < 16; ++e) acc[n][e] = 0.f;

  const float* __restrict__ arow = L + (size_t)(r0 + la) * NN + kb + koff;
  const unsigned short* __restrict__ bh_base = xfh + (size_t)kb * 128 + lane * 8;
  const unsigned short* __restrict__ bl_base = xfl + (size_t)kb * 128 + lane * 8;

  f4_t pa[32], pb[32];
  #pragma unroll
  for (int s = 0; s < 4; ++s) {
    pa[s] = __builtin_nontemporal_load((const f4_t*)(arow + s * 16));
    pb[s] = __builtin_nontemporal_load((const f4_t*)(arow + s * 16 + 4));
  }
  #pragma unroll
  for (int s = 0; s < 32; ++s) {
    if (s + 4 < 32) {
      pa[s + 4] = __builtin_nontemporal_load((const f4_t*)(arow + (s + 4) * 16));
      pb[s + 4] = __builtin_nontemporal_load((const f4_t*)(arow + (s + 4) * 16 + 4));
    }
    BFU ah, al;
    #pragma unroll
    for (int i = 0; i < 8; ++i) {
      const float f = (i < 4) ? pa[s][i] : pb[s][i - 4];
      const unsigned short h = f2bf(f);
      ah.u[i] = h;
      al.u[i] = f2bf(f - bf2f(h));
    }
    const unsigned short* __restrict__ bh_s = bh_base + s * 2048;
    const unsigned short* __restrict__ bl_s = bl_base + s * 2048;
    #pragma unroll
    for (int n = 0; n < 4; ++n) {
      const bf8v bh = *(const bf8v*)(bh_s + n * 512);
      const bf8v bl = *(const bf8v*)(bl_s + n * 512);
      acc[n] = __builtin_amdgcn_mfma_f32_32x32x16_bf16(ah.v, bh, acc[n], 0, 0, 0);
      acc[n] = __builtin_amdgcn_mfma_f32_32x32x16_bf16(al.v, bh, acc[n], 0, 0, 0);
      acc[n] = __builtin_amdgcn_mfma_f32_32x32x16_bf16(ah.v, bl, acc[n], 0, 0, 0);
    }
  }

  __shared__ float red[4][32][128];
  if (w < 4) {
    #pragma unroll
    for (int n = 0; n < 4; ++n)
      #pragma unroll
      for (int reg = 0; reg < 16; ++reg) {
        const int row = (reg & 3) + 8*(reg >> 2) + 4*(lane >> 5);
        red[w][row][32*n + la] = acc[n][reg];
      }
  }
  __syncthreads();
  if (w >= 4) {
    #pragma unroll
    for (int n = 0; n < 4; ++n)
      #pragma unroll
      for (int reg = 0; reg < 16; ++reg) {
        const int row = (reg & 3) + 8*(reg >> 2) + 4*(lane >> 5);
        red[w - 4][row][32*n + la] += acc[n][reg];
      }
  }
  __syncthreads();
  {
    const int row = t >> 4;
    const int c0 = (t & 15) * 8;
    #pragma unroll
    for (int j = 0; j < 8; ++j) {
      const int c = c0 + j;
      Hx[(size_t)(r0 + row) * 128 + c] =
          red[0][row][c] + red[1][row][c] + red[2][row][c] + red[3][row][c];
    }
  }
}

// ---------------------------------------------------------------------------
// U-GEMMs: U = x@W0 + Hx@W1, emitted as bf16 hi/lo FRAGMENTS.
__global__ __launch_bounds__(256) void k_ugemm(
    const float* __restrict__ x, const float* __restrict__ Wi_w,
    const float* __restrict__ Ws_w, float* __restrict__ ws,
    unsigned short* __restrict__ uih, unsigned short* __restrict__ uil,
    unsigned short* __restrict__ ush, unsigned short* __restrict__ usl) {
  const int rb = blockIdx.x;
  const int sel = blockIdx.y;
  const float* A[2]; const float* W[2];
  unsigned short* uh; unsigned short* ul;
  if (sel == 0) { A[0]=x; W[0]=Wi_w; A[1]=ws+HXI_OFF; W[1]=Wi_w+16384; uh=uih; ul=uil; }
  else          { A[0]=x; W[0]=Ws_w; A[1]=ws+HXS_OFF; W[1]=Ws_w+16384; uh=ush; ul=usl; }

  __shared__ __align__(16) float At[32][33];
  __shared__ __align__(16) float Wt[32][144];
  const int t = threadIdx.x;
  const int rg = t >> 4, cg = t & 15;
  const int r0 = rb * 32;
  float acc[2][8];
  #pragma unroll
  for (int i = 0; i < 2; ++i)
    #pragma unroll
    for (int j = 0; j < 8; ++j) acc[i][j] = 0.f;

  for (int ps = 0; ps < 2; ++ps) {
    const float* __restrict__ Ap = A[ps];
    const float* __restrict__ Wp = W[ps];
    for (int k0 = 0; k0 < 128; k0 += 32) {
      __syncthreads();
      {
        const int row = t >> 3, kq = t & 7;
        const float4 av = *(const float4*)&Ap[(r0 + row)*128 + k0 + kq*4];
        At[row][kq*4+0] = av.x; At[row][kq*4+1] = av.y;
        At[row][kq*4+2] = av.z; At[row][kq*4+3] = av.w;
      }
      #pragma unroll
      for (int l = 0; l < 4; ++l) {
        const int idx = t + l*256;
        const int kr = idx >> 5, c4 = idx & 31;
        const float4 wv = *(const float4*)&Wp[(k0 + kr)*128 + c4*4];
        *(float4*)&Wt[kr][XI(c4*4)] = wv;
      }
      __syncthreads();
      #pragma unroll
      for (int k = 0; k < 32; ++k) {
        const float a0 = At[rg*2 + 0][k];
        const float a1 = At[rg*2 + 1][k];
        const float4 b0 = *(const float4*)&Wt[k][XI(cg*8)];
        const float4 b1 = *(const float4*)&Wt[k][XI(cg*8 + 4)];
        acc[0][0] += a0*b0.x; acc[0][1] += a0*b0.y; acc[0][2] += a0*b0.z; acc[0][3] += a0*b0.w;
        acc[0][4] += a0*b1.x; acc[0][5] += a0*b1.y; acc[0][6] += a0*b1.z; acc[0][7] += a0*b1.w;
        acc[1][0] += a1*b0.x; acc[1][1] += a1*b0.y; acc[1][2] += a1*b0.z; acc[1][3] += a1*b0.w;
        acc[1][4] += a1*b1.x; acc[1][5] += a1*b1.y; acc[1][6] += a1*b1.z; acc[1][7] += a1*b1.w;
      }
    }
  }
  #pragma unroll
  for (int i = 0; i < 2; ++i) {
    const int r = r0 + rg*2 + i;
    #pragma unroll
    for (int j = 0; j < 8; ++j) {
      const int c = cg*8 + j;
      const float val = acc[i][j];
      const unsigned short h = f2bf(val);
      const unsigned short l = f2bf(val - bf2f(h));
      const size_t fa = FRAG(c, r);
      uh[fa] = h;
      ul[fa] = l;
    }
  }
}

// ---------------------------------------------------------------------------
// Dense masked-softmax attention via MFMA, DEPTH-4 A-PREFETCH + fast exp.
__global__ __launch_bounds__(512) void k_attnmm(
    const float* __restrict__ Ld, const float* __restrict__ Lu,
    float* __restrict__ ws, const unsigned short* __restrict__ uih,
    const unsigned short* __restrict__ uil, const unsigned short* __restrict__ ush,
    const unsigned short* __restrict__ usl) {
  const int bid = blockIdx.x;
  const int br  = BMAP_BR(bid);
  const int rblk = BMAP_RBLK(bid);
  const int t = threadIdx.x;
  const int w = t >> 6, lane = t & 63;
  const int la = lane & 31;
  const int koff = (lane >> 5) * 8;
  const int r0 = rblk * 32;
  const int kb = w * 512;
  const float* __restrict__ L = br ? Lu : Ld;
  const unsigned short* __restrict__ ufh = br ? ush : uih;
  const unsigned short* __restrict__ ufl = br ? usl : uil;
  float* __restrict__ O = ws + (br ? OS_OFF : OI_OFF);
  const float s1v = ws[S_OFF + (br ? 2*NN : 0) + r0 + la];
  const float* __restrict__ s2p = ws + S_OFF + (br ? 3*NN : NN) + kb + koff;

  f32x16 acc[4];
  #pragma unroll
  for (int n = 0; n < 4; ++n)
    #pragma unroll
    for (int e = 0; e < 16; ++e) acc[n][e] = 0.f;
  float dp = 0.f;

  const float* __restrict__ arow = L + (size_t)(r0 + la) * NN + kb + koff;
  const unsigned short* __restrict__ bh_base = ufh + (size_t)kb * 128 + lane * 8;
  const unsigned short* __restrict__ bl_base = ufl + (size_t)kb * 128 + lane * 8;

  f4_t pa[32], pb[32];
  #pragma unroll
  for (int s = 0; s < 4; ++s) {
    pa[s] = __builtin_nontemporal_load((const f4_t*)(arow + s * 16));
    pb[s] = __builtin_nontemporal_load((const f4_t*)(arow + s * 16 + 4));
  }
  #pragma unroll
  for (int s = 0; s < 32; ++s) {
    if (s + 4 < 32) {
      pa[s + 4] = __builtin_nontemporal_load((const f4_t*)(arow + (s + 4) * 16));
      pb[s + 4] = __builtin_nontemporal_load((const f4_t*)(arow + (s + 4) * 16 + 4));
    }
    const f4_t s2a = *(const f4_t*)(s2p + s * 16);
    const f4_t s2b = *(const f4_t*)(s2p + s * 16 + 4);
    BFU eh, el;
    #pragma unroll
    for (int i = 0; i < 8; ++i) {
      const float Lv = (i < 4) ? pa[s][i] : pb[s][i - 4];
      const float s2 = (i < 4) ? s2a[i] : s2b[i - 4];
      const float sc = s1v + s2;
      const float scl = sc >= 0.f ? sc : SLOPE * sc;
      const float ex = (Lv != 0.f) ? __expf(scl) : 0.f;
      dp += ex;
      const unsigned short h = f2bf(ex);
      eh.u[i] = h;
      el.u[i] = f2bf(ex - bf2f(h));
    }
    const unsigned short* __restrict__ bh_s = bh_base + s * 2048;
    const unsigned short* __restrict__ bl_s = bl_base + s * 2048;
    #pragma unroll
    for (int n = 0; n < 4; ++n) {
      const bf8v bh = *(const bf8v*)(bh_s + n * 512);
      const bf8v bl = *(const bf8v*)(bl_s + n * 512);
      acc[n] = __builtin_amdgcn_mfma_f32_32x32x16_bf16(eh.v, bh, acc[n], 0, 0, 0);
      acc[n] = __builtin_amdgcn_mfma_f32_32x32x16_bf16(el.v, bh, acc[n], 0, 0, 0);
      acc[n] = __builtin_amdgcn_mfma_f32_32x32x16_bf16(eh.v, bl, acc[n], 0, 0, 0);
    }
  }
  dp += __shfl_xor(dp, 32);

  __shared__ float red[4][32][128];
  __shared__ float dsl[4][32];
  if (w < 4) {
    #pragma unroll
    for (int n = 0; n < 4; ++n)
      #pragma unroll
      for (int reg = 0; reg < 16; ++reg) {
        const int row = (reg & 3) + 8*(reg >> 2) + 4*(lane >> 5);
        red[w][row][32*n + la] = acc[n][reg];
      }
    if (lane < 32) dsl[w][la] = dp;
  }
  __syncthreads();
  if (w >= 4) {
    #pragma unroll
    for (int n = 0; n < 4; ++n)
      #pragma unroll
      for (int reg = 0; reg < 16; ++reg) {
        const int row = (reg & 3) + 8*(reg >> 2) + 4*(lane >> 5);
        red[w - 4][row][32*n + la] += acc[n][reg];
      }
    if (lane < 32) dsl[w - 4][la] += dp;
  }
  __syncthreads();
  {
    const int row = t >> 4;
    const int c0 = (t & 15) * 8;
    const float den = dsl[0][row] + dsl[1][row] + dsl[2][row] + dsl[3][row];
    const float rden = 1.f / den;
    #pragma unroll
    for (int j = 0; j < 8; ++j) {
      const int c = c0 + j;
      O[(size_t)(r0 + row) * 128 + c] =
          (red[0][row][c] + red[1][row][c] + red[2][row][c] + red[3][row][c]) * rden;
    }
  }
}

// ---------------------------------------------------------------------------
// Dense P @ xWh via MFMA, DEPTH-4 A-PREFETCH. BM=32, grid (128,8).
__global__ __launch_bounds__(256) void k_pgemm(
    const float* __restrict__ P, const unsigned short* __restrict__ xth,
    const unsigned short* __restrict__ xtl, float* __restrict__ zpart) {
  const int t = threadIdx.x;
  const int w = t >> 6, lane = t & 63;
  const int la = lane & 31;
  const int koff = (lane >> 5) * 8;
  const int r0 = blockIdx.x * 32;
  const int kz = blockIdx.y;
  const int kb = kz * 512 + w * 128;

  f32x16 acc[4];
  #pragma unroll
  for (int n = 0; n < 4; ++n)
    #pragma unroll
    for (int e = 0; e < 16; ++e) acc[n][e] = 0.f;

  const float* __restrict__ arow = P + (size_t)(r0 + la) * NN + kb + koff;
  const unsigned short* __restrict__ bh_base = xth + (size_t)kb * 128 + lane * 8;
  const unsigned short* __restrict__ bl_base = xtl + (size_t)kb * 128 + lane * 8;

  f4_t pa[8], pb[8];
  #pragma unroll
  for (int s = 0; s < 4; ++s) {
    pa[s] = __builtin_nontemporal_load((const f4_t*)(arow + s * 16));
    pb[s] = __builtin_nontemporal_load((const f4_t*)(arow + s * 16 + 4));
  }
  #pragma unroll
  for (int s = 0; s < 8; ++s) {
    if (s + 4 < 8) {
      pa[s + 4] = __builtin_nontemporal_load((const f4_t*)(arow + (s + 4) * 16));
      pb[s + 4] = __builtin_nontemporal_load((const f4_t*)(arow + (s + 4) * 16 + 4));
    }
    BFU ah, al;
    #pragma unroll
    for (int i = 0; i < 8; ++i) {
      const float f = (i < 4) ? pa[s][i] : pb[s][i - 4];
      const unsigned short h = f2bf(f);
      ah.u[i] = h;
      al.u[i] = f2bf(f - bf2f(h));
    }
    const unsigned short* __restrict__ bh_s = bh_base + s * 2048;
    const unsigned short* __restrict__ bl_s = bl_base + s * 2048;
    #pragma unroll
    for (int n = 0; n < 4; ++n) {
      const bf8v bh = *(const bf8v*)(bh_s + n * 512);
      const bf8v bl = *(const bf8v*)(bl_s + n * 512);
      acc[n] = __builtin_amdgcn_mfma_f32_32x32x16_bf16(ah.v, bh, acc[n], 0, 0, 0);
      acc[n] = __builtin_amdgcn_mfma_f32_32x32x16_bf16(al.v, bh, acc[n], 0, 0, 0);
      acc[n] = __builtin_amdgcn_mfma_f32_32x32x16_bf16(ah.v, bl, acc[n], 0, 0, 0);
    }
  }

  __shared__ float red[2][32][128];
  if (w < 2) {
    #pragma unroll
    for (int n = 0; n < 4; ++n)
      #pragma unroll
      for (int reg = 0; reg < 16; ++reg) {
        const int row = (reg & 3) + 8*(reg >> 2) + 4*(lane >> 5);
        red[w][row][32*n + la] = acc[n][reg];
      }
  }
  __syncthreads();
  if (w >= 2) {
    #pragma unroll
    for (int n = 0; n < 4; ++n)
      #pragma unroll
      for (int reg = 0; reg < 16; ++reg) {
        const int row = (reg & 3) + 8*(reg >> 2) + 4*(lane >> 5);
        red[w - 2][row][32*n + la] += acc[n][reg];
      }
  }
  __syncthreads();
  float* __restrict__ zp = zpart + (size_t)kz * NN * 128;
  #pragma unroll
  for (int i = 0; i < 8; ++i) {
    const int row = w * 8 + i;
    zp[(size_t)(r0 + row) * 128 + lane]      = red[0][row][lane]      + red[1][row][lane];
    zp[(size_t)(r0 + row) * 128 + 64 + lane] = red[0][row][64 + lane] + red[1][row][64 + lane];
  }
}

// ---------------------------------------------------------------------------
// z = O_irr + O_sol + sum_k zpart[k] + b_total
__global__ __launch_bounds__(256) void k_combine(const float* __restrict__ ws,
                                                 float* __restrict__ z) {
  const int i = blockIdx.x * 256 + threadIdx.x;
  const int col = i & 127;
  float acc = ws[BT_OFF + col] + ws[OI_OFF + i] + ws[OS_OFF + i];
  #pragma unroll
  for (int kz = 0; kz < 8; ++kz) acc += ws[ZP_OFF + kz*NN*128 + i];
  z[i] = acc;
}

// ---------------------------------------------------------------------------
extern "C" void kernel_launch(void* const* d_in, const int* in_sizes, int n_in,
                              void* d_out, int out_size, void* d_ws, size_t ws_size,
                              hipStream_t stream) {
  const float* x       = (const float*)d_in[0];
  const float* Lu      = (const float*)d_in[1];
  const float* Ld      = (const float*)d_in[2];
  const float* P       = (const float*)d_in[3];
  const float* Wi_w    = (const float*)d_in[4];
  const float* Wi_b    = (const float*)d_in[5];
  const float* Ws_w    = (const float*)d_in[6];
  const float* Ws_b    = (const float*)d_in[7];
  const float* Wh_w    = (const float*)d_in[8];
  const float* Wh_b    = (const float*)d_in[9];
  const float* att_irr = (const float*)d_in[10];
  const float* att_sol = (const float*)d_in[11];
  float* z  = (float*)d_out;
  float* ws = (float*)d_ws;
  float*          zpart = ws + ZP_OFF;
  unsigned short* xth   = (unsigned short*)(ws + XWH_OFF);
  unsigned short* xtl   = xth + (size_t)128 * NN;
  unsigned short* uih   = (unsigned short*)(ws + UI_OFF);
  unsigned short* uil   = uih + (size_t)128 * NN;
  unsigned short* ush   = (unsigned short*)(ws + US_OFF);
  unsigned short* usl   = ush + (size_t)128 * NN;
  unsigned short* xfh   = (unsigned short*)((char*)d_ws + XF_BYTE_OFF);
  unsigned short* xfl   = xfh + (size_t)128 * NN;

  k_prep<<<1, 128, 0, stream>>>(Wi_w, Wi_b, Ws_w, Ws_b, Wh_b, att_irr, att_sol, ws);
  k_pre2<<<1152, 256, 0, stream>>>(x, Wh_w, ws, xth, xtl, xfh, xfl);
  k_hxmm<<<256, 512, 0, stream>>>(Ld, Lu, xfh, xfl, ws);
  {
    dim3 g(128, 2);
    k_ugemm<<<g, 256, 0, stream>>>(x, Wi_w, Ws_w, ws, uih, uil, ush, usl);
  }
  k_attnmm<<<256, 512, 0, stream>>>(Ld, Lu, ws, uih, uil, ush, usl);
  {
    dim3 g(128, 8);
    k_pgemm<<<g, 256, 0, stream>>>(P, xth, xtl, zpart);
  }
  k_combine<<<NN * 128 / 256, 256, 0, stream>>>(ws, z);
}

// Round 10
// 422.680 us; speedup vs baseline: 1.0843x; 1.0843x over previous
//
#include <hip/hip_runtime.h>

#define NN 4096
#define SLOPE 0.2f

typedef float f4_t __attribute__((ext_vector_type(4)));
typedef __bf16 bf8v __attribute__((ext_vector_type(8)));
typedef float f32x16 __attribute__((ext_vector_type(16)));

// ---- workspace layout (float offsets unless noted) ----
#define V_OFF     0                        // v1i,v2i,v1s,v2s : 4*128
#define C_OFF     512                      // 4 score constants
#define BT_OFF    516                      // b_total[128]
#define S_OFF     1024                     // s1i,s2i,s1s,s2s : 4*4096
#define DEN_OFF   20480                    // softmax denominators: 2*4096
#define HXI_OFF   32768                    // Ld@x   [4096,128] fp32 (atomic-accumulated)
#define HXS_OFF   (HXI_OFF + NN*128)       // Lu@x
#define UI_OFF    (HXS_OFF + NN*128)       // U_irr bf16 hi/lo fragment buffers
#define US_OFF    (UI_OFF + NN*128)        // U_sol bf16 hi/lo fragment buffers
#define XWH_OFF   (US_OFF + NN*128)        // xwhT hi/lo bf16 fragment buffers
#define OI_OFF    (XWH_OFF + NN*128)       // O_irr fp32 UNNORMALIZED (atomic)
#define OS_OFF    (OI_OFF + NN*128)        // O_sol fp32 UNNORMALIZED (atomic)
#define ZP_OFF    (OS_OFF + NN*128)        // P@xWh split-K partials: 8 * [4096,128]
#define WS_FLOATS (ZP_OFF + 8*NN*128)
#define XF_BYTE_OFF ((size_t)WS_FLOATS * 4)   // x fragment hi/lo buffers (2 MB)

// Pad map for fp32 LDS GEMM tiles (4-way -> 2-way, free per m136).
#define XI(c)   ((c) + (((c) >> 5) << 2))   // [0,128) -> [0,140)

// MFMA-fragment layout (B operand, 32x32x16 bf16; verified r5-r9):
#define FRAG(c, k) ((size_t)((k) >> 4) * 2048 + (size_t)((c) >> 5) * 512 \
                    + (size_t)((((c) & 31) + 32 * (((k) >> 3) & 1)) * 8 + ((k) & 7)))

// bf16 round-to-nearest-even helpers
__device__ __forceinline__ unsigned short f2bf(float x) {
  unsigned u = __float_as_uint(x);
  return (unsigned short)((u + 0x7FFFu + ((u >> 16) & 1u)) >> 16);
}
__device__ __forceinline__ float bf2f(unsigned short h) {
  return __uint_as_float(((unsigned)h) << 16);
}
union BFU { unsigned short u[8]; bf8v v; };

// ---------------------------------------------------------------------------
// Prep: v-vectors so s1[i] = x[i,:]·v + c, b_total.
__global__ __launch_bounds__(128) void k_prep(
    const float* __restrict__ Wi_w, const float* __restrict__ Wi_b,
    const float* __restrict__ Ws_w, const float* __restrict__ Ws_b,
    const float* __restrict__ Wh_b, const float* __restrict__ att_irr,
    const float* __restrict__ att_sol, float* __restrict__ ws) {
  const int t = threadIdx.x;
  float v1i = 0.f, v2i = 0.f, v1s = 0.f, v2s = 0.f;
  for (int j = 0; j < 2; ++j) {
    for (int o = 0; o < 128; ++o) {
      const float wi = Wi_w[j*16384 + t*128 + o];
      const float wv = Ws_w[j*16384 + t*128 + o];
      v1i += wi * att_irr[j*128 + o];
      v2i += wi * att_irr[256 + j*128 + o];
      v1s += wv * att_sol[j*128 + o];
      v2s += wv * att_sol[256 + j*128 + o];
    }
  }
  ws[V_OFF + t]       = v1i;
  ws[V_OFF + 128 + t] = v2i;
  ws[V_OFF + 256 + t] = v1s;
  ws[V_OFF + 384 + t] = v2s;
  ws[BT_OFF + t] = Wi_b[t] + Wi_b[128 + t] + Ws_b[t] + Ws_b[128 + t] + Wh_b[t];
  if (t < 4) {
    const float* bb = (t < 2) ? Wi_b : Ws_b;
    const float* aa = ((t < 2) ? att_irr : att_sol) + ((t & 1) ? 256 : 0);
    float c = 0.f;
    for (int k = 0; k < 256; ++k) c += bb[k] * aa[k];
    ws[C_OFF + t] = c;
  }
}

// ---------------------------------------------------------------------------
// Zero the atomic-accumulated buffers: Hx (both), O (both), den.
__global__ __launch_bounds__(256) void k_zero(float* __restrict__ ws) {
  const size_t q = ((size_t)blockIdx.x * 256 + threadIdx.x) * 4;
  if (q < (size_t)2*NN*128) {
    *(f4_t*)&ws[HXI_OFF + q] = (f4_t){0.f, 0.f, 0.f, 0.f};
  } else if (q < (size_t)4*NN*128) {
    *(f4_t*)&ws[OI_OFF + (q - (size_t)2*NN*128)] = (f4_t){0.f, 0.f, 0.f, 0.f};
  } else {
    const size_t r = q - (size_t)4*NN*128;
    if (r < 2*NN) *(f4_t*)&ws[DEN_OFF + r] = (f4_t){0.f, 0.f, 0.f, 0.f};
  }
}

// ---------------------------------------------------------------------------
// Fused pre-pass: blocks 0..127 compute xWh = x@Wh -> bf16 hi/lo fragments;
// blocks 128..1151: scores + x -> bf16 hi/lo fragments (feeds k_hxmm).
__global__ __launch_bounds__(256) void k_pre2(
    const float* __restrict__ x, const float* __restrict__ Wh_w,
    float* __restrict__ ws, unsigned short* __restrict__ xth,
    unsigned short* __restrict__ xtl, unsigned short* __restrict__ xfh,
    unsigned short* __restrict__ xfl) {
  __shared__ __align__(16) float At[32][33];
  __shared__ __align__(16) float Wt[32][144];
  const int t = threadIdx.x;

  if (blockIdx.x < 128) {
    const int rb = blockIdx.x;
    const int rg = t >> 4, cg = t & 15;
    const int r0 = rb * 32;
    float acc[2][8];
    #pragma unroll
    for (int i = 0; i < 2; ++i)
      #pragma unroll
      for (int j = 0; j < 8; ++j) acc[i][j] = 0.f;
    for (int k0 = 0; k0 < 128; k0 += 32) {
      __syncthreads();
      {
        const int row = t >> 3, kq = t & 7;
        const float4 av = *(const float4*)&x[(r0 + row)*128 + k0 + kq*4];
        At[row][kq*4+0] = av.x; At[row][kq*4+1] = av.y;
        At[row][kq*4+2] = av.z; At[row][kq*4+3] = av.w;
      }
      #pragma unroll
      for (int l = 0; l < 4; ++l) {
        const int idx = t + l*256;
        const int kr = idx >> 5, c4 = idx & 31;
        const float4 wv = *(const float4*)&Wh_w[(k0 + kr)*128 + c4*4];
        *(float4*)&Wt[kr][XI(c4*4)] = wv;
      }
      __syncthreads();
      #pragma unroll
      for (int k = 0; k < 32; ++k) {
        const float a0 = At[rg*2 + 0][k];
        const float a1 = At[rg*2 + 1][k];
        const float4 b0 = *(const float4*)&Wt[k][XI(cg*8)];
        const float4 b1 = *(const float4*)&Wt[k][XI(cg*8 + 4)];
        acc[0][0] += a0*b0.x; acc[0][1] += a0*b0.y; acc[0][2] += a0*b0.z; acc[0][3] += a0*b0.w;
        acc[0][4] += a0*b1.x; acc[0][5] += a0*b1.y; acc[0][6] += a0*b1.z; acc[0][7] += a0*b1.w;
        acc[1][0] += a1*b0.x; acc[1][1] += a1*b0.y; acc[1][2] += a1*b0.z; acc[1][3] += a1*b0.w;
        acc[1][4] += a1*b1.x; acc[1][5] += a1*b1.y; acc[1][6] += a1*b1.z; acc[1][7] += a1*b1.w;
      }
    }
    #pragma unroll
    for (int i = 0; i < 2; ++i) {
      const int r = r0 + rg*2 + i;       // r = k-index of pgemm
      #pragma unroll
      for (int j = 0; j < 8; ++j) {
        const int c = cg*8 + j;
        const float val = acc[i][j];
        const unsigned short h = f2bf(val);
        const unsigned short l = f2bf(val - bf2f(h));
        const size_t fa = FRAG(c, r);
        xth[fa] = h;
        xtl[fa] = l;
      }
    }
  } else {
    const int wave = t >> 6, lane = t & 63;
    const int row = (blockIdx.x - 128) * 4 + wave;
    const float* v = ws + V_OFF;
    const float x0 = x[row*128 + lane];
    const float x1 = x[row*128 + 64 + lane];
    {
      const unsigned short h0 = f2bf(x0);
      const unsigned short l0 = f2bf(x0 - bf2f(h0));
      const size_t fa0 = FRAG(lane, row);
      xfh[fa0] = h0; xfl[fa0] = l0;
      const unsigned short h1 = f2bf(x1);
      const unsigned short l1 = f2bf(x1 - bf2f(h1));
      const size_t fa1 = FRAG(lane + 64, row);
      xfh[fa1] = h1; xfl[fa1] = l1;
    }
    float p0 = x0 * v[lane]       + x1 * v[64 + lane];
    float p1 = x0 * v[128 + lane] + x1 * v[192 + lane];
    float p2 = x0 * v[256 + lane] + x1 * v[320 + lane];
    float p3 = x0 * v[384 + lane] + x1 * v[448 + lane];
    #pragma unroll
    for (int off = 32; off; off >>= 1) {
      p0 += __shfl_down(p0, off);
      p1 += __shfl_down(p1, off);
      p2 += __shfl_down(p2, off);
      p3 += __shfl_down(p3, off);
    }
    if (lane == 0) {
      ws[S_OFF + row]          = p0 + ws[C_OFF + 0];
      ws[S_OFF + NN + row]     = p1 + ws[C_OFF + 1];
      ws[S_OFF + 2*NN + row]   = p2 + ws[C_OFF + 2];
      ws[S_OFF + 3*NN + row]   = p3 + ws[C_OFF + 3];
    }
  }
}

// ---------------------------------------------------------------------------
// Dense Hx = L@x via MFMA, v3: LDS-staged L-tiles (32x128 fp32, XOR-swizzled,
// reg-staged with T14 issue-early/write-late), wave-per-n-tile (acc = 16
// VGPRs), K-split 4 across blocks -> 1024 blocks (4/CU), atomicAdd partials.
// HBM pattern: 512-B contiguous runs per wave (vs 64-B scatter before).
__global__ __launch_bounds__(256) void k_hxmm(
    const float* __restrict__ Ld, const float* __restrict__ Lu,
    const unsigned short* __restrict__ xfh, const unsigned short* __restrict__ xfl,
    float* __restrict__ ws) {
  const int bid = blockIdx.x;
  const int br  = (bid >> 2) & 1;                    // XCD-aware branch split
  const int idx = ((bid >> 3) << 2) | (bid & 3);     // [0,512)
  const int rblk = idx & 127;
  const int kz   = idx >> 7;                         // [0,4)
  const int t = threadIdx.x;
  const int w = t >> 6, lane = t & 63;
  const int la = lane & 31, h = lane >> 5;
  const int r0 = rblk * 32;
  const int kc = kz * 1024;
  const float* __restrict__ L = br ? Lu : Ld;
  float* __restrict__ Hx = ws + (br ? HXS_OFF : HXI_OFF);

  __shared__ __align__(16) char buf[2][16384];       // 2 x 32x128 fp32 tiles

  f32x16 acc;
  #pragma unroll
  for (int e = 0; e < 16; ++e) acc[e] = 0.f;

  const int col4 = la;
  const unsigned short* __restrict__ bh0 = xfh + ((size_t)kc >> 4) * 2048 + w * 512 + lane * 8;
  const unsigned short* __restrict__ bl0 = xfl + ((size_t)kc >> 4) * 2048 + w * 512 + lane * 8;

  // T14: load tile 0 into regs
  f4_t rv[4];
  #pragma unroll
  for (int i = 0; i < 4; ++i) {
    const int row = w*8 + i*2 + h;
    rv[i] = *(const f4_t*)&L[(size_t)(r0 + row) * NN + kc + col4 * 4];
  }

  for (int tt = 0; tt < 8; ++tt) {
    char* bd = buf[tt & 1];
    #pragma unroll
    for (int i = 0; i < 4; ++i) {                    // swizzled ds_write
      const int row = w*8 + i*2 + h;
      *(f4_t*)(bd + row*512 + ((col4*16) ^ ((row & 15) << 4))) = rv[i];
    }
    __syncthreads();
    if (tt + 1 < 8) {                                // issue next-tile loads early
      const int kcol = kc + (tt + 1) * 128;
      #pragma unroll
      for (int i = 0; i < 4; ++i) {
        const int row = w*8 + i*2 + h;
        rv[i] = *(const f4_t*)&L[(size_t)(r0 + row) * NN + kcol + col4 * 4];
      }
    }
    // compute 8 K-steps from LDS tile
    const char* tb = buf[tt & 1];
    const int rowb = la * 512;
    const int mask = (la & 15) << 4;
    #pragma unroll
    for (int s = 0; s < 8; ++s) {
      const int k0 = s * 16;
      const int b0 = k0 * 4 + 32 * h;
      const f4_t a0 = *(const f4_t*)(tb + rowb + ((b0) ^ mask));
      const f4_t a1 = *(const f4_t*)(tb + rowb + ((b0 + 16) ^ mask));
      BFU ah, al;
      #pragma unroll
      for (int i = 0; i < 8; ++i) {
        const float f = (i < 4) ? a0[i] : a1[i - 4];
        const unsigned short hh = f2bf(f);
        ah.u[i] = hh;
        al.u[i] = f2bf(f - bf2f(hh));
      }
      const size_t bo = (size_t)(tt * 8 + s) * 2048;
      const bf8v bh = *(const bf8v*)(bh0 + bo);
      const bf8v bl = *(const bf8v*)(bl0 + bo);
      acc = __builtin_amdgcn_mfma_f32_32x32x16_bf16(ah.v, bh, acc, 0, 0, 0);
      acc = __builtin_amdgcn_mfma_f32_32x32x16_bf16(al.v, bh, acc, 0, 0, 0);
      acc = __builtin_amdgcn_mfma_f32_32x32x16_bf16(ah.v, bl, acc, 0, 0, 0);
    }
  }

  // atomic-accumulate this K-chunk's partial (D-layout verified r5-r9)
  #pragma unroll
  for (int reg = 0; reg < 16; ++reg) {
    const int row = (reg & 3) + 8*(reg >> 2) + 4*h;
    atomicAdd(&Hx[(size_t)(r0 + row) * 128 + 32*w + la], acc[reg]);
  }
}

// ---------------------------------------------------------------------------
// U-GEMMs: U = x@W0 + Hx@W1, emitted as bf16 hi/lo FRAGMENTS.
__global__ __launch_bounds__(256) void k_ugemm(
    const float* __restrict__ x, const float* __restrict__ Wi_w,
    const float* __restrict__ Ws_w, float* __restrict__ ws,
    unsigned short* __restrict__ uih, unsigned short* __restrict__ uil,
    unsigned short* __restrict__ ush, unsigned short* __restrict__ usl) {
  const int rb = blockIdx.x;
  const int sel = blockIdx.y;
  const float* A[2]; const float* W[2];
  unsigned short* uh; unsigned short* ul;
  if (sel == 0) { A[0]=x; W[0]=Wi_w; A[1]=ws+HXI_OFF; W[1]=Wi_w+16384; uh=uih; ul=uil; }
  else          { A[0]=x; W[0]=Ws_w; A[1]=ws+HXS_OFF; W[1]=Ws_w+16384; uh=ush; ul=usl; }

  __shared__ __align__(16) float At[32][33];
  __shared__ __align__(16) float Wt[32][144];
  const int t = threadIdx.x;
  const int rg = t >> 4, cg = t & 15;
  const int r0 = rb * 32;
  float acc[2][8];
  #pragma unroll
  for (int i = 0; i < 2; ++i)
    #pragma unroll
    for (int j = 0; j < 8; ++j) acc[i][j] = 0.f;

  for (int ps = 0; ps < 2; ++ps) {
    const float* __restrict__ Ap = A[ps];
    const float* __restrict__ Wp = W[ps];
    for (int k0 = 0; k0 < 128; k0 += 32) {
      __syncthreads();
      {
        const int row = t >> 3, kq = t & 7;
        const float4 av = *(const float4*)&Ap[(r0 + row)*128 + k0 + kq*4];
        At[row][kq*4+0] = av.x; At[row][kq*4+1] = av.y;
        At[row][kq*4+2] = av.z; At[row][kq*4+3] = av.w;
      }
      #pragma unroll
      for (int l = 0; l < 4; ++l) {
        const int idx = t + l*256;
        const int kr = idx >> 5, c4 = idx & 31;
        const float4 wv = *(const float4*)&Wp[(k0 + kr)*128 + c4*4];
        *(float4*)&Wt[kr][XI(c4*4)] = wv;
      }
      __syncthreads();
      #pragma unroll
      for (int k = 0; k < 32; ++k) {
        const float a0 = At[rg*2 + 0][k];
        const float a1 = At[rg*2 + 1][k];
        const float4 b0 = *(const float4*)&Wt[k][XI(cg*8)];
        const float4 b1 = *(const float4*)&Wt[k][XI(cg*8 + 4)];
        acc[0][0] += a0*b0.x; acc[0][1] += a0*b0.y; acc[0][2] += a0*b0.z; acc[0][3] += a0*b0.w;
        acc[0][4] += a0*b1.x; acc[0][5] += a0*b1.y; acc[0][6] += a0*b1.z; acc[0][7] += a0*b1.w;
        acc[1][0] += a1*b0.x; acc[1][1] += a1*b0.y; acc[1][2] += a1*b0.z; acc[1][3] += a1*b0.w;
        acc[1][4] += a1*b1.x; acc[1][5] += a1*b1.y; acc[1][6] += a1*b1.z; acc[1][7] += a1*b1.w;
      }
    }
  }
  #pragma unroll
  for (int i = 0; i < 2; ++i) {
    const int r = r0 + rg*2 + i;
    #pragma unroll
    for (int j = 0; j < 8; ++j) {
      const int c = cg*8 + j;
      const float val = acc[i][j];
      const unsigned short h = f2bf(val);
      const unsigned short l = f2bf(val - bf2f(h));
      const size_t fa = FRAG(c, r);
      uh[fa] = h;
      ul[fa] = l;
    }
  }
}

// ---------------------------------------------------------------------------
// Dense masked-softmax attention via MFMA, v3: same LDS-staged structure as
// k_hxmm; E computed on the fly from the staged L-tile (exp via __expf);
// unnormalized O + den accumulated atomically, normalization in k_combine.
__global__ __launch_bounds__(256) void k_attnmm(
    const float* __restrict__ Ld, const float* __restrict__ Lu,
    float* __restrict__ ws, const unsigned short* __restrict__ uih,
    const unsigned short* __restrict__ uil, const unsigned short* __restrict__ ush,
    const unsigned short* __restrict__ usl) {
  const int bid = blockIdx.x;
  const int br  = (bid >> 2) & 1;
  const int idx = ((bid >> 3) << 2) | (bid & 3);
  const int rblk = idx & 127;
  const int kz   = idx >> 7;
  const int t = threadIdx.x;
  const int w = t >> 6, lane = t & 63;
  const int la = lane & 31, h = lane >> 5;
  const int r0 = rblk * 32;
  const int kc = kz * 1024;
  const float* __restrict__ L = br ? Lu : Ld;
  const unsigned short* __restrict__ ufh = br ? ush : uih;
  const unsigned short* __restrict__ ufl = br ? usl : uil;
  float* __restrict__ O = ws + (br ? OS_OFF : OI_OFF);
  float* __restrict__ den = ws + DEN_OFF + br * NN;
  const float s1v = ws[S_OFF + (br ? 2*NN : 0) + r0 + la];
  const float* __restrict__ s2b = ws + S_OFF + (br ? 3*NN : NN) + kc;

  __shared__ __align__(16) char buf[2][16384];

  f32x16 acc;
  #pragma unroll
  for (int e = 0; e < 16; ++e) acc[e] = 0.f;
  float dp = 0.f;

  const int col4 = la;
  const unsigned short* __restrict__ bh0 = ufh + ((size_t)kc >> 4) * 2048 + w * 512 + lane * 8;
  const unsigned short* __restrict__ bl0 = ufl + ((size_t)kc >> 4) * 2048 + w * 512 + lane * 8;

  f4_t rv[4];
  #pragma unroll
  for (int i = 0; i < 4; ++i) {
    const int row = w*8 + i*2 + h;
    rv[i] = *(const f4_t*)&L[(size_t)(r0 + row) * NN + kc + col4 * 4];
  }

  for (int tt = 0; tt < 8; ++tt) {
    char* bd = buf[tt & 1];
    #pragma unroll
    for (int i = 0; i < 4; ++i) {
      const int row = w*8 + i*2 + h;
      *(f4_t*)(bd + row*512 + ((col4*16) ^ ((row & 15) << 4))) = rv[i];
    }
    __syncthreads();
    if (tt + 1 < 8) {
      const int kcol = kc + (tt + 1) * 128;
      #pragma unroll
      for (int i = 0; i < 4; ++i) {
        const int row = w*8 + i*2 + h;
        rv[i] = *(const f4_t*)&L[(size_t)(r0 + row) * NN + kcol + col4 * 4];
      }
    }
    const char* tb = buf[tt & 1];
    const int rowb = la * 512;
    const int mask = (la & 15) << 4;
    #pragma unroll
    for (int s = 0; s < 8; ++s) {
      const int k0 = s * 16;
      const int b0 = k0 * 4 + 32 * h;
      const f4_t a0 = *(const f4_t*)(tb + rowb + ((b0) ^ mask));
      const f4_t a1 = *(const f4_t*)(tb + rowb + ((b0 + 16) ^ mask));
      const int kloc = tt * 128 + k0 + 8 * h;
      const f4_t s2a = *(const f4_t*)(s2b + kloc);
      const f4_t s2c = *(const f4_t*)(s2b + kloc + 4);
      BFU eh, el;
      #pragma unroll
      for (int i = 0; i < 8; ++i) {
        const float Lv = (i < 4) ? a0[i] : a1[i - 4];
        const float s2 = (i < 4) ? s2a[i] : s2c[i - 4];
        const float sc = s1v + s2;
        const float scl = sc >= 0.f ? sc : SLOPE * sc;
        const float ex = (Lv != 0.f) ? __expf(scl) : 0.f;
        dp += ex;
        const unsigned short hh = f2bf(ex);
        eh.u[i] = hh;
        el.u[i] = f2bf(ex - bf2f(hh));
      }
      const size_t bo = (size_t)(tt * 8 + s) * 2048;
      const bf8v bh = *(const bf8v*)(bh0 + bo);
      const bf8v bl = *(const bf8v*)(bl0 + bo);
      acc = __builtin_amdgcn_mfma_f32_32x32x16_bf16(eh.v, bh, acc, 0, 0, 0);
      acc = __builtin_amdgcn_mfma_f32_32x32x16_bf16(el.v, bh, acc, 0, 0, 0);
      acc = __builtin_amdgcn_mfma_f32_32x32x16_bf16(eh.v, bl, acc, 0, 0, 0);
    }
  }
  // den: lanes la and la+32 hold the two k-halves of row la; all 4 waves
  // compute identical E -> only wave 0 contributes.
  dp += __shfl_xor(dp, 32);
  if (w == 0 && lane < 32) atomicAdd(&den[r0 + la], dp);

  #pragma unroll
  for (int reg = 0; reg < 16; ++reg) {
    const int row = (reg & 3) + 8*(reg >> 2) + 4*h;
    atomicAdd(&O[(size_t)(r0 + row) * 128 + 32*w + la], acc[reg]);
  }
}

// ---------------------------------------------------------------------------
// Dense P @ xWh via MFMA (round-6 form): BM=32, grid (128,8), fragment-
// ordered B, nt A-loads with one-step prefetch.
__global__ __launch_bounds__(256) void k_pgemm(
    const float* __restrict__ P, const unsigned short* __restrict__ xth,
    const unsigned short* __restrict__ xtl, float* __restrict__ zpart) {
  const int t = threadIdx.x;
  const int w = t >> 6, lane = t & 63;
  const int la = lane & 31;
  const int koff = (lane >> 5) * 8;
  const int r0 = blockIdx.x * 32;
  const int kz = blockIdx.y;
  const int kb = kz * 512 + w * 128;

  f32x16 acc[4];
  #pragma unroll
  for (int n = 0; n < 4; ++n)
    #pragma unroll
    for (int e = 0; e < 16; ++e) acc[n][e] = 0.f;

  const float* __restrict__ arow = P + (size_t)(r0 + la) * NN + kb + koff;
  const unsigned short* __restrict__ bh_base = xth + (size_t)kb * 128 + lane * 8;
  const unsigned short* __restrict__ bl_base = xtl + (size_t)kb * 128 + lane * 8;

  f4_t a0 = __builtin_nontemporal_load((const f4_t*)arow);
  f4_t a1 = __builtin_nontemporal_load((const f4_t*)(arow + 4));
  for (int s = 0; s < 8; ++s) {
    f4_t na0 = a0, na1 = a1;
    if (s < 7) {
      na0 = __builtin_nontemporal_load((const f4_t*)(arow + (s + 1) * 16));
      na1 = __builtin_nontemporal_load((const f4_t*)(arow + (s + 1) * 16 + 4));
    }
    BFU ah, al;
    #pragma unroll
    for (int i = 0; i < 8; ++i) {
      const float f = (i < 4) ? a0[i] : a1[i - 4];
      const unsigned short h = f2bf(f);
      ah.u[i] = h;
      al.u[i] = f2bf(f - bf2f(h));
    }
    const unsigned short* __restrict__ bh_s = bh_base + s * 2048;
    const unsigned short* __restrict__ bl_s = bl_base + s * 2048;
    #pragma unroll
    for (int n = 0; n < 4; ++n) {
      const bf8v bh = *(const bf8v*)(bh_s + n * 512);
      const bf8v bl = *(const bf8v*)(bl_s + n * 512);
      acc[n] = __builtin_amdgcn_mfma_f32_32x32x16_bf16(ah.v, bh, acc[n], 0, 0, 0);
      acc[n] = __builtin_amdgcn_mfma_f32_32x32x16_bf16(al.v, bh, acc[n], 0, 0, 0);
      acc[n] = __builtin_amdgcn_mfma_f32_32x32x16_bf16(ah.v, bl, acc[n], 0, 0, 0);
    }
    a0 = na0; a1 = na1;
  }

  __shared__ float red[2][32][128];
  if (w < 2) {
    #pragma unroll
    for (int n = 0; n < 4; ++n)
      #pragma unroll
      for (int reg = 0; reg < 16; ++reg) {
        const int row = (reg & 3) + 8*(reg >> 2) + 4*(lane >> 5);
        red[w][row][32*n + la] = acc[n][reg];
      }
  }
  __syncthreads();
  if (w >= 2) {
    #pragma unroll
    for (int n = 0; n < 4; ++n)
      #pragma unroll
      for (int reg = 0; reg < 16; ++reg) {
        const int row = (reg & 3) + 8*(reg >> 2) + 4*(lane >> 5);
        red[w - 2][row][32*n + la] += acc[n][reg];
      }
  }
  __syncthreads();
  float* __restrict__ zp = zpart + (size_t)kz * NN * 128;
  #pragma unroll
  for (int i = 0; i < 8; ++i) {
    const int row = w * 8 + i;
    zp[(size_t)(r0 + row) * 128 + lane]      = red[0][row][lane]      + red[1][row][lane];
    zp[(size_t)(r0 + row) * 128 + 64 + lane] = red[0][row][64 + lane] + red[1][row][64 + lane];
  }
}

// ---------------------------------------------------------------------------
// z = O_irr/den_irr + O_sol/den_sol + sum_k zpart[k] + b_total
__global__ __launch_bounds__(256) void k_combine(const float* __restrict__ ws,
                                                 float* __restrict__ z) {
  const int i = blockIdx.x * 256 + threadIdx.x;
  const int col = i & 127;
  const int row = i >> 7;
  const float di = ws[DEN_OFF + row];
  const float ds = ws[DEN_OFF + NN + row];
  float acc = ws[BT_OFF + col] + ws[OI_OFF + i] / di + ws[OS_OFF + i] / ds;
  #pragma unroll
  for (int kz = 0; kz < 8; ++kz) acc += ws[ZP_OFF + kz*NN*128 + i];
  z[i] = acc;
}

// ---------------------------------------------------------------------------
extern "C" void kernel_launch(void* const* d_in, const int* in_sizes, int n_in,
                              void* d_out, int out_size, void* d_ws, size_t ws_size,
                              hipStream_t stream) {
  const float* x       = (const float*)d_in[0];
  const float* Lu      = (const float*)d_in[1];
  const float* Ld      = (const float*)d_in[2];
  const float* P       = (const float*)d_in[3];
  const float* Wi_w    = (const float*)d_in[4];
  const float* Wi_b    = (const float*)d_in[5];
  const float* Ws_w    = (const float*)d_in[6];
  const float* Ws_b    = (const float*)d_in[7];
  const float* Wh_w    = (const float*)d_in[8];
  const float* Wh_b    = (const float*)d_in[9];
  const float* att_irr = (const float*)d_in[10];
  const float* att_sol = (const float*)d_in[11];
  float* z  = (float*)d_out;
  float* ws = (float*)d_ws;
  float*          zpart = ws + ZP_OFF;
  unsigned short* xth   = (unsigned short*)(ws + XWH_OFF);
  unsigned short* xtl   = xth + (size_t)128 * NN;
  unsigned short* uih   = (unsigned short*)(ws + UI_OFF);
  unsigned short* uil   = uih + (size_t)128 * NN;
  unsigned short* ush   = (unsigned short*)(ws + US_OFF);
  unsigned short* usl   = ush + (size_t)128 * NN;
  unsigned short* xfh   = (unsigned short*)((char*)d_ws + XF_BYTE_OFF);
  unsigned short* xfl   = xfh + (size_t)128 * NN;

  k_prep<<<1, 128, 0, stream>>>(Wi_w, Wi_b, Ws_w, Ws_b, Wh_b, att_irr, att_sol, ws);
  k_zero<<<(4*NN*128 + 2*NN) / 1024, 256, 0, stream>>>(ws);
  k_pre2<<<1152, 256, 0, stream>>>(x, Wh_w, ws, xth, xtl, xfh, xfl);
  k_hxmm<<<1024, 256, 0, stream>>>(Ld, Lu, xfh, xfl, ws);
  {
    dim3 g(128, 2);
    k_ugemm<<<g, 256, 0, stream>>>(x, Wi_w, Ws_w, ws, uih, uil, ush, usl);
  }
  k_attnmm<<<1024, 256, 0, stream>>>(Ld, Lu, ws, uih, uil, ush, usl);
  {
    dim3 g(128, 8);
    k_pgemm<<<g, 256, 0, stream>>>(P, xth, xtl, zpart);
  }
  k_combine<<<NN * 128 / 256, 256, 0, stream>>>(ws, z);
}

// Round 11
// 394.902 us; speedup vs baseline: 1.1606x; 1.0703x over previous
//
#include <hip/hip_runtime.h>

#define NN 4096
#define SLOPE 0.2f

typedef float f4_t __attribute__((ext_vector_type(4)));
typedef __bf16 bf8v __attribute__((ext_vector_type(8)));
typedef float f32x16 __attribute__((ext_vector_type(16)));

// ---- workspace layout (float offsets unless noted) ----
#define V_OFF     0                        // v1i,v2i,v1s,v2s : 4*128
#define C_OFF     512                      // 4 score constants
#define BT_OFF    516                      // b_total[128]
#define S_OFF     1024                     // s1i,s2i,s1s,s2s : 4*4096
#define DEN_OFF   20480                    // softmax denominators: 2*4096
#define HXI_OFF   32768                    // Ld@x   [4096,128] fp32 (atomic-accumulated)
#define HXS_OFF   (HXI_OFF + NN*128)       // Lu@x
#define UI_OFF    (HXS_OFF + NN*128)       // U_irr bf16 hi/lo fragment buffers
#define US_OFF    (UI_OFF + NN*128)        // U_sol bf16 hi/lo fragment buffers
#define XWH_OFF   (US_OFF + NN*128)        // xwhT hi/lo bf16 fragment buffers
#define OI_OFF    (XWH_OFF + NN*128)       // O_irr fp32 UNNORMALIZED (atomic)
#define OS_OFF    (OI_OFF + NN*128)        // O_sol fp32 UNNORMALIZED (atomic)
#define ZP_OFF    (OS_OFF + NN*128)        // P@xWh split-K partials: 8 * [4096,128]
#define WS_FLOATS (ZP_OFF + 8*NN*128)
#define XF_BYTE_OFF ((size_t)WS_FLOATS * 4)   // x fragment hi/lo buffers (2 MB)

// Pad map for fp32 LDS GEMM tiles (4-way -> 2-way, free per m136).
#define XI(c)   ((c) + (((c) >> 5) << 2))   // [0,128) -> [0,140)

// MFMA-fragment layout (B operand, 32x32x16 bf16; verified r5-r10):
#define FRAG(c, k) ((size_t)((k) >> 4) * 2048 + (size_t)((c) >> 5) * 512 \
                    + (size_t)((((c) & 31) + 32 * (((k) >> 3) & 1)) * 8 + ((k) & 7)))

// bf16 round-to-nearest-even helpers
__device__ __forceinline__ unsigned short f2bf(float x) {
  unsigned u = __float_as_uint(x);
  return (unsigned short)((u + 0x7FFFu + ((u >> 16) & 1u)) >> 16);
}
__device__ __forceinline__ float bf2f(unsigned short h) {
  return __uint_as_float(((unsigned)h) << 16);
}
union BFU { unsigned short u[8]; bf8v v; };
union P8 { unsigned short u[4]; unsigned long long ull; };

// ---------------------------------------------------------------------------
// Prep: v-vectors so s1[i] = x[i,:]·v + c, b_total.
__global__ __launch_bounds__(128) void k_prep(
    const float* __restrict__ Wi_w, const float* __restrict__ Wi_b,
    const float* __restrict__ Ws_w, const float* __restrict__ Ws_b,
    const float* __restrict__ Wh_b, const float* __restrict__ att_irr,
    const float* __restrict__ att_sol, float* __restrict__ ws) {
  const int t = threadIdx.x;
  float v1i = 0.f, v2i = 0.f, v1s = 0.f, v2s = 0.f;
  for (int j = 0; j < 2; ++j) {
    for (int o = 0; o < 128; ++o) {
      const float wi = Wi_w[j*16384 + t*128 + o];
      const float wv = Ws_w[j*16384 + t*128 + o];
      v1i += wi * att_irr[j*128 + o];
      v2i += wi * att_irr[256 + j*128 + o];
      v1s += wv * att_sol[j*128 + o];
      v2s += wv * att_sol[256 + j*128 + o];
    }
  }
  ws[V_OFF + t]       = v1i;
  ws[V_OFF + 128 + t] = v2i;
  ws[V_OFF + 256 + t] = v1s;
  ws[V_OFF + 384 + t] = v2s;
  ws[BT_OFF + t] = Wi_b[t] + Wi_b[128 + t] + Ws_b[t] + Ws_b[128 + t] + Wh_b[t];
  if (t < 4) {
    const float* bb = (t < 2) ? Wi_b : Ws_b;
    const float* aa = ((t < 2) ? att_irr : att_sol) + ((t & 1) ? 256 : 0);
    float c = 0.f;
    for (int k = 0; k < 256; ++k) c += bb[k] * aa[k];
    ws[C_OFF + t] = c;
  }
}

// ---------------------------------------------------------------------------
// Zero the atomic-accumulated buffers: Hx (both), O (both), den.
__global__ __launch_bounds__(256) void k_zero(float* __restrict__ ws) {
  const size_t q = ((size_t)blockIdx.x * 256 + threadIdx.x) * 4;
  if (q < (size_t)2*NN*128) {
    *(f4_t*)&ws[HXI_OFF + q] = (f4_t){0.f, 0.f, 0.f, 0.f};
  } else if (q < (size_t)4*NN*128) {
    *(f4_t*)&ws[OI_OFF + (q - (size_t)2*NN*128)] = (f4_t){0.f, 0.f, 0.f, 0.f};
  } else {
    const size_t r = q - (size_t)4*NN*128;
    if (r < 2*NN) *(f4_t*)&ws[DEN_OFF + r] = (f4_t){0.f, 0.f, 0.f, 0.f};
  }
}

// ---------------------------------------------------------------------------
// Fused pre-pass: blocks 0..127 compute xWh = x@Wh -> bf16 hi/lo fragments;
// blocks 128..1151: scores + x -> bf16 hi/lo fragments (feeds k_hxmm).
__global__ __launch_bounds__(256) void k_pre2(
    const float* __restrict__ x, const float* __restrict__ Wh_w,
    float* __restrict__ ws, unsigned short* __restrict__ xth,
    unsigned short* __restrict__ xtl, unsigned short* __restrict__ xfh,
    unsigned short* __restrict__ xfl) {
  __shared__ __align__(16) float At[32][33];
  __shared__ __align__(16) float Wt[32][144];
  const int t = threadIdx.x;

  if (blockIdx.x < 128) {
    const int rb = blockIdx.x;
    const int rg = t >> 4, cg = t & 15;
    const int r0 = rb * 32;
    float acc[2][8];
    #pragma unroll
    for (int i = 0; i < 2; ++i)
      #pragma unroll
      for (int j = 0; j < 8; ++j) acc[i][j] = 0.f;
    for (int k0 = 0; k0 < 128; k0 += 32) {
      __syncthreads();
      {
        const int row = t >> 3, kq = t & 7;
        const float4 av = *(const float4*)&x[(r0 + row)*128 + k0 + kq*4];
        At[row][kq*4+0] = av.x; At[row][kq*4+1] = av.y;
        At[row][kq*4+2] = av.z; At[row][kq*4+3] = av.w;
      }
      #pragma unroll
      for (int l = 0; l < 4; ++l) {
        const int idx = t + l*256;
        const int kr = idx >> 5, c4 = idx & 31;
        const float4 wv = *(const float4*)&Wh_w[(k0 + kr)*128 + c4*4];
        *(float4*)&Wt[kr][XI(c4*4)] = wv;
      }
      __syncthreads();
      #pragma unroll
      for (int k = 0; k < 32; ++k) {
        const float a0 = At[rg*2 + 0][k];
        const float a1 = At[rg*2 + 1][k];
        const float4 b0 = *(const float4*)&Wt[k][XI(cg*8)];
        const float4 b1 = *(const float4*)&Wt[k][XI(cg*8 + 4)];
        acc[0][0] += a0*b0.x; acc[0][1] += a0*b0.y; acc[0][2] += a0*b0.z; acc[0][3] += a0*b0.w;
        acc[0][4] += a0*b1.x; acc[0][5] += a0*b1.y; acc[0][6] += a0*b1.z; acc[0][7] += a0*b1.w;
        acc[1][0] += a1*b0.x; acc[1][1] += a1*b0.y; acc[1][2] += a1*b0.z; acc[1][3] += a1*b0.w;
        acc[1][4] += a1*b1.x; acc[1][5] += a1*b1.y; acc[1][6] += a1*b1.z; acc[1][7] += a1*b1.w;
      }
    }
    #pragma unroll
    for (int i = 0; i < 2; ++i) {
      const int r = r0 + rg*2 + i;       // r = k-index of pgemm
      #pragma unroll
      for (int j = 0; j < 8; ++j) {
        const int c = cg*8 + j;
        const float val = acc[i][j];
        const unsigned short h = f2bf(val);
        const unsigned short l = f2bf(val - bf2f(h));
        const size_t fa = FRAG(c, r);
        xth[fa] = h;
        xtl[fa] = l;
      }
    }
  } else {
    const int wave = t >> 6, lane = t & 63;
    const int row = (blockIdx.x - 128) * 4 + wave;
    const float* v = ws + V_OFF;
    const float x0 = x[row*128 + lane];
    const float x1 = x[row*128 + 64 + lane];
    {
      const unsigned short h0 = f2bf(x0);
      const unsigned short l0 = f2bf(x0 - bf2f(h0));
      const size_t fa0 = FRAG(lane, row);
      xfh[fa0] = h0; xfl[fa0] = l0;
      const unsigned short h1 = f2bf(x1);
      const unsigned short l1 = f2bf(x1 - bf2f(h1));
      const size_t fa1 = FRAG(lane + 64, row);
      xfh[fa1] = h1; xfl[fa1] = l1;
    }
    float p0 = x0 * v[lane]       + x1 * v[64 + lane];
    float p1 = x0 * v[128 + lane] + x1 * v[192 + lane];
    float p2 = x0 * v[256 + lane] + x1 * v[320 + lane];
    float p3 = x0 * v[384 + lane] + x1 * v[448 + lane];
    #pragma unroll
    for (int off = 32; off; off >>= 1) {
      p0 += __shfl_down(p0, off);
      p1 += __shfl_down(p1, off);
      p2 += __shfl_down(p2, off);
      p3 += __shfl_down(p3, off);
    }
    if (lane == 0) {
      ws[S_OFF + row]          = p0 + ws[C_OFF + 0];
      ws[S_OFF + NN + row]     = p1 + ws[C_OFF + 1];
      ws[S_OFF + 2*NN + row]   = p2 + ws[C_OFF + 2];
      ws[S_OFF + 3*NN + row]   = p3 + ws[C_OFF + 3];
    }
  }
}

// ---------------------------------------------------------------------------
// Dense Hx = L@x via MFMA, v4: SHARED A-FRAGMENTS. Stage phase converts each
// L element ONCE into bf16 hi/lo A-fragment layout in LDS (8B packed scatter,
// XOR-by-step swizzle -> 2-way writes); all 4 waves ds_read ready fragments.
// Double-buffered, 1 barrier/tile, next-tile loads issued before the barrier.
// Grid: 2br x 128rblk x 4kz = 1024 blocks (4/CU); atomicAdd K-partials.
__global__ __launch_bounds__(256) void k_hxmm(
    const float* __restrict__ Ld, const float* __restrict__ Lu,
    const unsigned short* __restrict__ xfh, const unsigned short* __restrict__ xfl,
    float* __restrict__ ws) {
  const int bid = blockIdx.x;
  const int br  = (bid >> 2) & 1;
  const int idx = ((bid >> 3) << 2) | (bid & 3);
  const int rblk = idx & 127;
  const int kz   = idx >> 7;
  const int t = threadIdx.x;
  const int w = t >> 6, lane = t & 63;
  const int la = lane & 31, h = lane >> 5;
  const int r0 = rblk * 32;
  const int kc = kz * 1024;
  const float* __restrict__ L = br ? Lu : Ld;
  float* __restrict__ Hx = ws + (br ? HXS_OFF : HXI_OFF);

  __shared__ __align__(16) char ahb[2][8192];
  __shared__ __align__(16) char alb[2][8192];

  f32x16 acc;
  #pragma unroll
  for (int e = 0; e < 16; ++e) acc[e] = 0.f;

  // stage scatter constants: this thread's step, j-offset, lane_t addend
  const int s_t   = la >> 2;
  const int xmask = s_t << 4;
  const int j0b   = (la & 1) * 8;
  const int lt_add = 32 * ((la >> 1) & 1);

  const unsigned short* __restrict__ bh0 = xfh + ((size_t)kc >> 4) * 2048 + w * 512 + lane * 8;
  const unsigned short* __restrict__ bl0 = xfl + ((size_t)kc >> 4) * 2048 + w * 512 + lane * 8;

  f4_t rv[4], nv[4];
  #pragma unroll
  for (int i = 0; i < 4; ++i) {
    const int row = w*8 + i*2 + h;
    rv[i] = *(const f4_t*)&L[(size_t)(r0 + row) * NN + kc + la * 4];
  }
  // convert tile 0 -> buf 0
  #pragma unroll
  for (int i = 0; i < 4; ++i) {
    const int row = w*8 + i*2 + h;
    const int off = s_t*1024 + (((row + lt_add)*16) ^ xmask) + j0b;
    P8 ph, pl;
    #pragma unroll
    for (int c = 0; c < 4; ++c) {
      const float f = rv[i][c];
      const unsigned short hh = f2bf(f);
      ph.u[c] = hh;
      pl.u[c] = f2bf(f - bf2f(hh));
    }
    *(unsigned long long*)(ahb[0] + off) = ph.ull;
    *(unsigned long long*)(alb[0] + off) = pl.ull;
  }

  #pragma unroll
  for (int tt = 0; tt < 8; ++tt) {
    const int cur = tt & 1;
    if (tt < 7) {   // issue next-tile loads early; consumed after compute
      #pragma unroll
      for (int i = 0; i < 4; ++i) {
        const int row = w*8 + i*2 + h;
        nv[i] = *(const f4_t*)&L[(size_t)(r0 + row) * NN + kc + (tt+1)*128 + la * 4];
      }
    }
    __syncthreads();   // buf[cur] fully written
    #pragma unroll
    for (int s = 0; s < 8; ++s) {
      const int ra = s*1024 + ((lane*16) ^ (s << 4));
      const bf8v ah = *(const bf8v*)(ahb[cur] + ra);
      const bf8v al = *(const bf8v*)(alb[cur] + ra);
      const size_t bo = (size_t)(tt * 8 + s) * 2048;
      const bf8v bh = *(const bf8v*)(bh0 + bo);
      const bf8v bl = *(const bf8v*)(bl0 + bo);
      acc = __builtin_amdgcn_mfma_f32_32x32x16_bf16(ah, bh, acc, 0, 0, 0);
      acc = __builtin_amdgcn_mfma_f32_32x32x16_bf16(al, bh, acc, 0, 0, 0);
      acc = __builtin_amdgcn_mfma_f32_32x32x16_bf16(ah, bl, acc, 0, 0, 0);
    }
    if (tt < 7) {   // convert next tile into the other buffer
      #pragma unroll
      for (int i = 0; i < 4; ++i) {
        const int row = w*8 + i*2 + h;
        const int off = s_t*1024 + (((row + lt_add)*16) ^ xmask) + j0b;
        P8 ph, pl;
        #pragma unroll
        for (int c = 0; c < 4; ++c) {
          const float f = nv[i][c];
          const unsigned short hh = f2bf(f);
          ph.u[c] = hh;
          pl.u[c] = f2bf(f - bf2f(hh));
        }
        *(unsigned long long*)(ahb[cur ^ 1] + off) = ph.ull;
        *(unsigned long long*)(alb[cur ^ 1] + off) = pl.ull;
      }
    }
  }

  #pragma unroll
  for (int reg = 0; reg < 16; ++reg) {
    const int row = (reg & 3) + 8*(reg >> 2) + 4*h;
    atomicAdd(&Hx[(size_t)(r0 + row) * 128 + 32*w + la], acc[reg]);
  }
}

// ---------------------------------------------------------------------------
// U-GEMMs: U = x@W0 + Hx@W1, emitted as bf16 hi/lo FRAGMENTS.
__global__ __launch_bounds__(256) void k_ugemm(
    const float* __restrict__ x, const float* __restrict__ Wi_w,
    const float* __restrict__ Ws_w, float* __restrict__ ws,
    unsigned short* __restrict__ uih, unsigned short* __restrict__ uil,
    unsigned short* __restrict__ ush, unsigned short* __restrict__ usl) {
  const int rb = blockIdx.x;
  const int sel = blockIdx.y;
  const float* A[2]; const float* W[2];
  unsigned short* uh; unsigned short* ul;
  if (sel == 0) { A[0]=x; W[0]=Wi_w; A[1]=ws+HXI_OFF; W[1]=Wi_w+16384; uh=uih; ul=uil; }
  else          { A[0]=x; W[0]=Ws_w; A[1]=ws+HXS_OFF; W[1]=Ws_w+16384; uh=ush; ul=usl; }

  __shared__ __align__(16) float At[32][33];
  __shared__ __align__(16) float Wt[32][144];
  const int t = threadIdx.x;
  const int rg = t >> 4, cg = t & 15;
  const int r0 = rb * 32;
  float acc[2][8];
  #pragma unroll
  for (int i = 0; i < 2; ++i)
    #pragma unroll
    for (int j = 0; j < 8; ++j) acc[i][j] = 0.f;

  for (int ps = 0; ps < 2; ++ps) {
    const float* __restrict__ Ap = A[ps];
    const float* __restrict__ Wp = W[ps];
    for (int k0 = 0; k0 < 128; k0 += 32) {
      __syncthreads();
      {
        const int row = t >> 3, kq = t & 7;
        const float4 av = *(const float4*)&Ap[(r0 + row)*128 + k0 + kq*4];
        At[row][kq*4+0] = av.x; At[row][kq*4+1] = av.y;
        At[row][kq*4+2] = av.z; At[row][kq*4+3] = av.w;
      }
      #pragma unroll
      for (int l = 0; l < 4; ++l) {
        const int idx = t + l*256;
        const int kr = idx >> 5, c4 = idx & 31;
        const float4 wv = *(const float4*)&Wp[(k0 + kr)*128 + c4*4];
        *(float4*)&Wt[kr][XI(c4*4)] = wv;
      }
      __syncthreads();
      #pragma unroll
      for (int k = 0; k < 32; ++k) {
        const float a0 = At[rg*2 + 0][k];
        const float a1 = At[rg*2 + 1][k];
        const float4 b0 = *(const float4*)&Wt[k][XI(cg*8)];
        const float4 b1 = *(const float4*)&Wt[k][XI(cg*8 + 4)];
        acc[0][0] += a0*b0.x; acc[0][1] += a0*b0.y; acc[0][2] += a0*b0.z; acc[0][3] += a0*b0.w;
        acc[0][4] += a0*b1.x; acc[0][5] += a0*b1.y; acc[0][6] += a0*b1.z; acc[0][7] += a0*b1.w;
        acc[1][0] += a1*b0.x; acc[1][1] += a1*b0.y; acc[1][2] += a1*b0.z; acc[1][3] += a1*b0.w;
        acc[1][4] += a1*b1.x; acc[1][5] += a1*b1.y; acc[1][6] += a1*b1.z; acc[1][7] += a1*b1.w;
      }
    }
  }
  #pragma unroll
  for (int i = 0; i < 2; ++i) {
    const int r = r0 + rg*2 + i;
    #pragma unroll
    for (int j = 0; j < 8; ++j) {
      const int c = cg*8 + j;
      const float val = acc[i][j];
      const unsigned short h = f2bf(val);
      const unsigned short l = f2bf(val - bf2f(h));
      const size_t fa = FRAG(c, r);
      uh[fa] = h;
      ul[fa] = l;
    }
  }
}

// ---------------------------------------------------------------------------
// Dense masked-softmax attention via MFMA, v4: SHARED E-FRAGMENTS. Stage
// phase computes E = (L!=0)?exp(leaky(s1+s2)):0 ONCE per element, packs bf16
// hi/lo fragments to LDS; dp accumulated per-thread during conversion and
// shfl-reduced per row at the end. Same pipeline as k_hxmm.
__global__ __launch_bounds__(256) void k_attnmm(
    const float* __restrict__ Ld, const float* __restrict__ Lu,
    float* __restrict__ ws, const unsigned short* __restrict__ uih,
    const unsigned short* __restrict__ uil, const unsigned short* __restrict__ ush,
    const unsigned short* __restrict__ usl) {
  const int bid = blockIdx.x;
  const int br  = (bid >> 2) & 1;
  const int idx = ((bid >> 3) << 2) | (bid & 3);
  const int rblk = idx & 127;
  const int kz   = idx >> 7;
  const int t = threadIdx.x;
  const int w = t >> 6, lane = t & 63;
  const int la = lane & 31, h = lane >> 5;
  const int r0 = rblk * 32;
  const int kc = kz * 1024;
  const float* __restrict__ L = br ? Lu : Ld;
  const unsigned short* __restrict__ ufh = br ? ush : uih;
  const unsigned short* __restrict__ ufl = br ? usl : uil;
  float* __restrict__ O = ws + (br ? OS_OFF : OI_OFF);
  float* __restrict__ den = ws + DEN_OFF + br * NN;
  const float* __restrict__ s1b = ws + S_OFF + (br ? 2*NN : 0) + r0;
  const float* __restrict__ s2b = ws + S_OFF + (br ? 3*NN : NN) + kc;

  __shared__ __align__(16) char ahb[2][8192];
  __shared__ __align__(16) char alb[2][8192];

  f32x16 acc;
  #pragma unroll
  for (int e = 0; e < 16; ++e) acc[e] = 0.f;
  float dp[4] = {0.f, 0.f, 0.f, 0.f};

  const int s_t   = la >> 2;
  const int xmask = s_t << 4;
  const int j0b   = (la & 1) * 8;
  const int lt_add = 32 * ((la >> 1) & 1);

  float s1r[4];
  #pragma unroll
  for (int i = 0; i < 4; ++i) s1r[i] = s1b[w*8 + i*2 + h];

  const unsigned short* __restrict__ bh0 = ufh + ((size_t)kc >> 4) * 2048 + w * 512 + lane * 8;
  const unsigned short* __restrict__ bl0 = ufl + ((size_t)kc >> 4) * 2048 + w * 512 + lane * 8;

  f4_t rv[4], nv[4];
  #pragma unroll
  for (int i = 0; i < 4; ++i) {
    const int row = w*8 + i*2 + h;
    rv[i] = *(const f4_t*)&L[(size_t)(r0 + row) * NN + kc + la * 4];
  }
  // convert tile 0 -> buf 0
  {
    const f4_t s2v = *(const f4_t*)(s2b + la * 4);
    #pragma unroll
    for (int i = 0; i < 4; ++i) {
      const int row = w*8 + i*2 + h;
      const int off = s_t*1024 + (((row + lt_add)*16) ^ xmask) + j0b;
      P8 ph, pl;
      #pragma unroll
      for (int c = 0; c < 4; ++c) {
        const float sc = s1r[i] + s2v[c];
        const float scl = sc >= 0.f ? sc : SLOPE * sc;
        const float ex = (rv[i][c] != 0.f) ? __expf(scl) : 0.f;
        dp[i] += ex;
        const unsigned short hh = f2bf(ex);
        ph.u[c] = hh;
        pl.u[c] = f2bf(ex - bf2f(hh));
      }
      *(unsigned long long*)(ahb[0] + off) = ph.ull;
      *(unsigned long long*)(alb[0] + off) = pl.ull;
    }
  }

  #pragma unroll
  for (int tt = 0; tt < 8; ++tt) {
    const int cur = tt & 1;
    if (tt < 7) {
      #pragma unroll
      for (int i = 0; i < 4; ++i) {
        const int row = w*8 + i*2 + h;
        nv[i] = *(const f4_t*)&L[(size_t)(r0 + row) * NN + kc + (tt+1)*128 + la * 4];
      }
    }
    __syncthreads();
    #pragma unroll
    for (int s = 0; s < 8; ++s) {
      const int ra = s*1024 + ((lane*16) ^ (s << 4));
      const bf8v ah = *(const bf8v*)(ahb[cur] + ra);
      const bf8v al = *(const bf8v*)(alb[cur] + ra);
      const size_t bo = (size_t)(tt * 8 + s) * 2048;
      const bf8v bh = *(const bf8v*)(bh0 + bo);
      const bf8v bl = *(const bf8v*)(bl0 + bo);
      acc = __builtin_amdgcn_mfma_f32_32x32x16_bf16(ah, bh, acc, 0, 0, 0);
      acc = __builtin_amdgcn_mfma_f32_32x32x16_bf16(al, bh, acc, 0, 0, 0);
      acc = __builtin_amdgcn_mfma_f32_32x32x16_bf16(ah, bl, acc, 0, 0, 0);
    }
    if (tt < 7) {
      const f4_t s2v = *(const f4_t*)(s2b + (tt+1)*128 + la * 4);
      #pragma unroll
      for (int i = 0; i < 4; ++i) {
        const int row = w*8 + i*2 + h;
        const int off = s_t*1024 + (((row + lt_add)*16) ^ xmask) + j0b;
        P8 ph, pl;
        #pragma unroll
        for (int c = 0; c < 4; ++c) {
          const float sc = s1r[i] + s2v[c];
          const float scl = sc >= 0.f ? sc : SLOPE * sc;
          const float ex = (nv[i][c] != 0.f) ? __expf(scl) : 0.f;
          dp[i] += ex;
          const unsigned short hh = f2bf(ex);
          ph.u[c] = hh;
          pl.u[c] = f2bf(ex - bf2f(hh));
        }
        *(unsigned long long*)(ahb[cur ^ 1] + off) = ph.ull;
        *(unsigned long long*)(alb[cur ^ 1] + off) = pl.ull;
      }
    }
  }

  // per-row denominator: reduce over the 32 la-lanes of each half-wave
  #pragma unroll
  for (int i = 0; i < 4; ++i) {
    #pragma unroll
    for (int off = 16; off; off >>= 1) dp[i] += __shfl_xor(dp[i], off);
  }
  if (la == 0) {
    #pragma unroll
    for (int i = 0; i < 4; ++i)
      atomicAdd(&den[r0 + w*8 + i*2 + h], dp[i]);
  }

  #pragma unroll
  for (int reg = 0; reg < 16; ++reg) {
    const int row = (reg & 3) + 8*(reg >> 2) + 4*h;
    atomicAdd(&O[(size_t)(r0 + row) * 128 + 32*w + la], acc[reg]);
  }
}

// ---------------------------------------------------------------------------
// Dense P @ xWh via MFMA (round-6 form): BM=32, grid (128,8), fragment-
// ordered B, nt A-loads with one-step prefetch.
__global__ __launch_bounds__(256) void k_pgemm(
    const float* __restrict__ P, const unsigned short* __restrict__ xth,
    const unsigned short* __restrict__ xtl, float* __restrict__ zpart) {
  const int t = threadIdx.x;
  const int w = t >> 6, lane = t & 63;
  const int la = lane & 31;
  const int koff = (lane >> 5) * 8;
  const int r0 = blockIdx.x * 32;
  const int kz = blockIdx.y;
  const int kb = kz * 512 + w * 128;

  f32x16 acc[4];
  #pragma unroll
  for (int n = 0; n < 4; ++n)
    #pragma unroll
    for (int e = 0; e < 16; ++e) acc[n][e] = 0.f;

  const float* __restrict__ arow = P + (size_t)(r0 + la) * NN + kb + koff;
  const unsigned short* __restrict__ bh_base = xth + (size_t)kb * 128 + lane * 8;
  const unsigned short* __restrict__ bl_base = xtl + (size_t)kb * 128 + lane * 8;

  f4_t a0 = __builtin_nontemporal_load((const f4_t*)arow);
  f4_t a1 = __builtin_nontemporal_load((const f4_t*)(arow + 4));
  for (int s = 0; s < 8; ++s) {
    f4_t na0 = a0, na1 = a1;
    if (s < 7) {
      na0 = __builtin_nontemporal_load((const f4_t*)(arow + (s + 1) * 16));
      na1 = __builtin_nontemporal_load((const f4_t*)(arow + (s + 1) * 16 + 4));
    }
    BFU ah, al;
    #pragma unroll
    for (int i = 0; i < 8; ++i) {
      const float f = (i < 4) ? a0[i] : a1[i - 4];
      const unsigned short h = f2bf(f);
      ah.u[i] = h;
      al.u[i] = f2bf(f - bf2f(h));
    }
    const unsigned short* __restrict__ bh_s = bh_base + s * 2048;
    const unsigned short* __restrict__ bl_s = bl_base + s * 2048;
    #pragma unroll
    for (int n = 0; n < 4; ++n) {
      const bf8v bh = *(const bf8v*)(bh_s + n * 512);
      const bf8v bl = *(const bf8v*)(bl_s + n * 512);
      acc[n] = __builtin_amdgcn_mfma_f32_32x32x16_bf16(ah.v, bh, acc[n], 0, 0, 0);
      acc[n] = __builtin_amdgcn_mfma_f32_32x32x16_bf16(al.v, bh, acc[n], 0, 0, 0);
      acc[n] = __builtin_amdgcn_mfma_f32_32x32x16_bf16(ah.v, bl, acc[n], 0, 0, 0);
    }
    a0 = na0; a1 = na1;
  }

  __shared__ float red[2][32][128];
  if (w < 2) {
    #pragma unroll
    for (int n = 0; n < 4; ++n)
      #pragma unroll
      for (int reg = 0; reg < 16; ++reg) {
        const int row = (reg & 3) + 8*(reg >> 2) + 4*(lane >> 5);
        red[w][row][32*n + la] = acc[n][reg];
      }
  }
  __syncthreads();
  if (w >= 2) {
    #pragma unroll
    for (int n = 0; n < 4; ++n)
      #pragma unroll
      for (int reg = 0; reg < 16; ++reg) {
        const int row = (reg & 3) + 8*(reg >> 2) + 4*(lane >> 5);
        red[w - 2][row][32*n + la] += acc[n][reg];
      }
  }
  __syncthreads();
  float* __restrict__ zp = zpart + (size_t)kz * NN * 128;
  #pragma unroll
  for (int i = 0; i < 8; ++i) {
    const int row = w * 8 + i;
    zp[(size_t)(r0 + row) * 128 + lane]      = red[0][row][lane]      + red[1][row][lane];
    zp[(size_t)(r0 + row) * 128 + 64 + lane] = red[0][row][64 + lane] + red[1][row][64 + lane];
  }
}

// ---------------------------------------------------------------------------
// z = O_irr/den_irr + O_sol/den_sol + sum_k zpart[k] + b_total
__global__ __launch_bounds__(256) void k_combine(const float* __restrict__ ws,
                                                 float* __restrict__ z) {
  const int i = blockIdx.x * 256 + threadIdx.x;
  const int col = i & 127;
  const int row = i >> 7;
  const float di = ws[DEN_OFF + row];
  const float ds = ws[DEN_OFF + NN + row];
  float acc = ws[BT_OFF + col] + ws[OI_OFF + i] / di + ws[OS_OFF + i] / ds;
  #pragma unroll
  for (int kz = 0; kz < 8; ++kz) acc += ws[ZP_OFF + kz*NN*128 + i];
  z[i] = acc;
}

// ---------------------------------------------------------------------------
extern "C" void kernel_launch(void* const* d_in, const int* in_sizes, int n_in,
                              void* d_out, int out_size, void* d_ws, size_t ws_size,
                              hipStream_t stream) {
  const float* x       = (const float*)d_in[0];
  const float* Lu      = (const float*)d_in[1];
  const float* Ld      = (const float*)d_in[2];
  const float* P       = (const float*)d_in[3];
  const float* Wi_w    = (const float*)d_in[4];
  const float* Wi_b    = (const float*)d_in[5];
  const float* Ws_w    = (const float*)d_in[6];
  const float* Ws_b    = (const float*)d_in[7];
  const float* Wh_w    = (const float*)d_in[8];
  const float* Wh_b    = (const float*)d_in[9];
  const float* att_irr = (const float*)d_in[10];
  const float* att_sol = (const float*)d_in[11];
  float* z  = (float*)d_out;
  float* ws = (float*)d_ws;
  float*          zpart = ws + ZP_OFF;
  unsigned short* xth   = (unsigned short*)(ws + XWH_OFF);
  unsigned short* xtl   = xth + (size_t)128 * NN;
  unsigned short* uih   = (unsigned short*)(ws + UI_OFF);
  unsigned short* uil   = uih + (size_t)128 * NN;
  unsigned short* ush   = (unsigned short*)(ws + US_OFF);
  unsigned short* usl   = ush + (size_t)128 * NN;
  unsigned short* xfh   = (unsigned short*)((char*)d_ws + XF_BYTE_OFF);
  unsigned short* xfl   = xfh + (size_t)128 * NN;

  k_prep<<<1, 128, 0, stream>>>(Wi_w, Wi_b, Ws_w, Ws_b, Wh_b, att_irr, att_sol, ws);
  k_zero<<<(4*NN*128 + 2*NN) / 1024, 256, 0, stream>>>(ws);
  k_pre2<<<1152, 256, 0, stream>>>(x, Wh_w, ws, xth, xtl, xfh, xfl);
  k_hxmm<<<1024, 256, 0, stream>>>(Ld, Lu, xfh, xfl, ws);
  {
    dim3 g(128, 2);
    k_ugemm<<<g, 256, 0, stream>>>(x, Wi_w, Ws_w, ws, uih, uil, ush, usl);
  }
  k_attnmm<<<1024, 256, 0, stream>>>(Ld, Lu, ws, uih, uil, ush, usl);
  {
    dim3 g(128, 8);
    k_pgemm<<<g, 256, 0, stream>>>(P, xth, xtl, zpart);
  }
  k_combine<<<NN * 128 / 256, 256, 0, stream>>>(ws, z);
}

// Round 12
// 359.085 us; speedup vs baseline: 1.2764x; 1.0997x over previous
//
#include <hip/hip_runtime.h>

#define NN 4096
#define SLOPE 0.2f

typedef float f4_t __attribute__((ext_vector_type(4)));
typedef __bf16 bf8v __attribute__((ext_vector_type(8)));
typedef float f32x16 __attribute__((ext_vector_type(16)));

// ---- workspace layout (float offsets unless noted) ----
#define V_OFF     0                        // v1i,v2i,v1s,v2s : 4*128
#define C_OFF     512                      // 4 score constants
#define BT_OFF    516                      // b_total[128]
#define S_OFF     1024                     // s1i,s2i,s1s,s2s : 4*4096
#define HXI_OFF   32768                    // Ld@x kz0 [4096,128]; later REUSED as O_irr kz1
#define HXS_OFF   (HXI_OFF + NN*128)       // Lu@x kz0; later O_sol kz1
#define UI_OFF    (HXS_OFF + NN*128)       // U_irr bf16 hi/lo fragment buffers
#define US_OFF    (UI_OFF + NN*128)        // U_sol bf16 hi/lo fragment buffers
#define XWH_OFF   (US_OFF + NN*128)        // xwhT hi/lo bf16 fragment buffers
#define OI_OFF    (XWH_OFF + NN*128)       // O_irr kz0
#define OS_OFF    (OI_OFF + NN*128)        // O_sol kz0
#define ZP_OFF    (OS_OFF + NN*128)        // P@xWh split-K partials: 8 * [4096,128]
#define WS_FLOATS (ZP_OFF + 8*NN*128)
// tail (bytes): x frags (2MB) | Hx kz1 partials (4MB) | denominators (64KB)
#define XF_BYTE_OFF  ((size_t)WS_FLOATS * 4)
#define HX2_BYTE_OFF (XF_BYTE_OFF + (size_t)2*1024*1024)
#define DEN_BYTE_OFF (HX2_BYTE_OFF + (size_t)4*1024*1024)

// Pad map for fp32 LDS GEMM tiles (4-way -> 2-way, free per m136).
#define XI(c)   ((c) + (((c) >> 5) << 2))   // [0,128) -> [0,140)

// MFMA-fragment layout (B operand, 32x32x16 bf16; verified r5-r11):
#define FRAG(c, k) ((size_t)((k) >> 4) * 2048 + (size_t)((c) >> 5) * 512 \
                    + (size_t)((((c) & 31) + 32 * (((k) >> 3) & 1)) * 8 + ((k) & 7)))

// bf16 round-to-nearest-even helpers
__device__ __forceinline__ unsigned short f2bf(float x) {
  unsigned u = __float_as_uint(x);
  return (unsigned short)((u + 0x7FFFu + ((u >> 16) & 1u)) >> 16);
}
__device__ __forceinline__ float bf2f(unsigned short h) {
  return __uint_as_float(((unsigned)h) << 16);
}
union BFU { unsigned short u[8]; bf8v v; };

// ---------------------------------------------------------------------------
// Prep: v-vectors so s1[i] = x[i,:]·v + c, b_total.
__global__ __launch_bounds__(128) void k_prep(
    const float* __restrict__ Wi_w, const float* __restrict__ Wi_b,
    const float* __restrict__ Ws_w, const float* __restrict__ Ws_b,
    const float* __restrict__ Wh_b, const float* __restrict__ att_irr,
    const float* __restrict__ att_sol, float* __restrict__ ws) {
  const int t = threadIdx.x;
  float v1i = 0.f, v2i = 0.f, v1s = 0.f, v2s = 0.f;
  for (int j = 0; j < 2; ++j) {
    for (int o = 0; o < 128; ++o) {
      const float wi = Wi_w[j*16384 + t*128 + o];
      const float wv = Ws_w[j*16384 + t*128 + o];
      v1i += wi * att_irr[j*128 + o];
      v2i += wi * att_irr[256 + j*128 + o];
      v1s += wv * att_sol[j*128 + o];
      v2s += wv * att_sol[256 + j*128 + o];
    }
  }
  ws[V_OFF + t]       = v1i;
  ws[V_OFF + 128 + t] = v2i;
  ws[V_OFF + 256 + t] = v1s;
  ws[V_OFF + 384 + t] = v2s;
  ws[BT_OFF + t] = Wi_b[t] + Wi_b[128 + t] + Ws_b[t] + Ws_b[128 + t] + Wh_b[t];
  if (t < 4) {
    const float* bb = (t < 2) ? Wi_b : Ws_b;
    const float* aa = ((t < 2) ? att_irr : att_sol) + ((t & 1) ? 256 : 0);
    float c = 0.f;
    for (int k = 0; k < 256; ++k) c += bb[k] * aa[k];
    ws[C_OFF + t] = c;
  }
}

// ---------------------------------------------------------------------------
// Fused pre-pass: blocks 0..127 compute xWh = x@Wh -> bf16 hi/lo fragments;
// blocks 128..1151: scores + x -> bf16 hi/lo fragments (feeds k_hxmm).
__global__ __launch_bounds__(256) void k_pre2(
    const float* __restrict__ x, const float* __restrict__ Wh_w,
    float* __restrict__ ws, unsigned short* __restrict__ xth,
    unsigned short* __restrict__ xtl, unsigned short* __restrict__ xfh,
    unsigned short* __restrict__ xfl) {
  __shared__ __align__(16) float At[32][33];
  __shared__ __align__(16) float Wt[32][144];
  const int t = threadIdx.x;

  if (blockIdx.x < 128) {
    const int rb = blockIdx.x;
    const int rg = t >> 4, cg = t & 15;
    const int r0 = rb * 32;
    float acc[2][8];
    #pragma unroll
    for (int i = 0; i < 2; ++i)
      #pragma unroll
      for (int j = 0; j < 8; ++j) acc[i][j] = 0.f;
    for (int k0 = 0; k0 < 128; k0 += 32) {
      __syncthreads();
      {
        const int row = t >> 3, kq = t & 7;
        const float4 av = *(const float4*)&x[(r0 + row)*128 + k0 + kq*4];
        At[row][kq*4+0] = av.x; At[row][kq*4+1] = av.y;
        At[row][kq*4+2] = av.z; At[row][kq*4+3] = av.w;
      }
      #pragma unroll
      for (int l = 0; l < 4; ++l) {
        const int idx = t + l*256;
        const int kr = idx >> 5, c4 = idx & 31;
        const float4 wv = *(const float4*)&Wh_w[(k0 + kr)*128 + c4*4];
        *(float4*)&Wt[kr][XI(c4*4)] = wv;
      }
      __syncthreads();
      #pragma unroll
      for (int k = 0; k < 32; ++k) {
        const float a0 = At[rg*2 + 0][k];
        const float a1 = At[rg*2 + 1][k];
        const float4 b0 = *(const float4*)&Wt[k][XI(cg*8)];
        const float4 b1 = *(const float4*)&Wt[k][XI(cg*8 + 4)];
        acc[0][0] += a0*b0.x; acc[0][1] += a0*b0.y; acc[0][2] += a0*b0.z; acc[0][3] += a0*b0.w;
        acc[0][4] += a0*b1.x; acc[0][5] += a0*b1.y; acc[0][6] += a0*b1.z; acc[0][7] += a0*b1.w;
        acc[1][0] += a1*b0.x; acc[1][1] += a1*b0.y; acc[1][2] += a1*b0.z; acc[1][3] += a1*b0.w;
        acc[1][4] += a1*b1.x; acc[1][5] += a1*b1.y; acc[1][6] += a1*b1.z; acc[1][7] += a1*b1.w;
      }
    }
    #pragma unroll
    for (int i = 0; i < 2; ++i) {
      const int r = r0 + rg*2 + i;       // r = k-index of pgemm
      #pragma unroll
      for (int j = 0; j < 8; ++j) {
        const int c = cg*8 + j;
        const float val = acc[i][j];
        const unsigned short h = f2bf(val);
        const unsigned short l = f2bf(val - bf2f(h));
        const size_t fa = FRAG(c, r);
        xth[fa] = h;
        xtl[fa] = l;
      }
    }
  } else {
    const int wave = t >> 6, lane = t & 63;
    const int row = (blockIdx.x - 128) * 4 + wave;
    const float* v = ws + V_OFF;
    const float x0 = x[row*128 + lane];
    const float x1 = x[row*128 + 64 + lane];
    {
      const unsigned short h0 = f2bf(x0);
      const unsigned short l0 = f2bf(x0 - bf2f(h0));
      const size_t fa0 = FRAG(lane, row);
      xfh[fa0] = h0; xfl[fa0] = l0;
      const unsigned short h1 = f2bf(x1);
      const unsigned short l1 = f2bf(x1 - bf2f(h1));
      const size_t fa1 = FRAG(lane + 64, row);
      xfh[fa1] = h1; xfl[fa1] = l1;
    }
    float p0 = x0 * v[lane]       + x1 * v[64 + lane];
    float p1 = x0 * v[128 + lane] + x1 * v[192 + lane];
    float p2 = x0 * v[256 + lane] + x1 * v[320 + lane];
    float p3 = x0 * v[384 + lane] + x1 * v[448 + lane];
    #pragma unroll
    for (int off = 32; off; off >>= 1) {
      p0 += __shfl_down(p0, off);
      p1 += __shfl_down(p1, off);
      p2 += __shfl_down(p2, off);
      p3 += __shfl_down(p3, off);
    }
    if (lane == 0) {
      ws[S_OFF + row]          = p0 + ws[C_OFF + 0];
      ws[S_OFF + NN + row]     = p1 + ws[C_OFF + 1];
      ws[S_OFF + 2*NN + row]   = p2 + ws[C_OFF + 2];
      ws[S_OFF + 3*NN + row]   = p3 + ws[C_OFF + 3];
    }
  }
}

// ---------------------------------------------------------------------------
// Dense Hx = L@x via MFMA, v5: NO ATOMICS. Grid 2br x 128rblk x 2kz = 512
// blocks (2/CU), 512 threads = 8 waves (4 n-tiles x 2 step-parities).
// Stage: 8 elems/thread -> packed 16B fragment stores (swizzled). Parity
// pairs LDS-reduce at the end; kz partials to separate buffers.
__global__ __launch_bounds__(512) void k_hxmm(
    const float* __restrict__ Ld, const float* __restrict__ Lu,
    const unsigned short* __restrict__ xfh, const unsigned short* __restrict__ xfl,
    float* __restrict__ ws, float* __restrict__ hx2) {
  const int bid = blockIdx.x;
  const int br  = (bid >> 2) & 1;                   // XCD-aware branch split
  const int rest = ((bid >> 3) << 2) | (bid & 3);   // [0,256)
  const int rblk = rest & 127;
  const int kz   = rest >> 7;                       // [0,2)
  const int t = threadIdx.x;
  const int lane = t & 63;
  const int n = (t >> 6) & 3, par = t >> 8;         // wave = 4n x 2par
  const int r0 = rblk * 32;
  const int kbase = kz * 2048;
  const float* __restrict__ L = br ? Lu : Ld;
  float* __restrict__ out = kz ? (hx2 + (size_t)br * NN * 128)
                               : (ws + (br ? HXS_OFF : HXI_OFF));

  __shared__ __align__(16) char ahb[2][8192];
  __shared__ __align__(16) char alb[2][8192];

  f32x16 acc;
  #pragma unroll
  for (int e = 0; e < 16; ++e) acc[e] = 0.f;

  // stage mapping: thread covers (row = t>>4, k = kg..kg+7), one 16B slot
  const int srow = t >> 4;
  const int kg   = (t & 15) * 8;
  const int sS   = kg >> 4;
  const int lt   = srow + 32 * ((kg >> 3) & 1);
  const int soff = (sS * 64 + (lt ^ sS)) * 16;

  const float* __restrict__ lrow = L + (size_t)(r0 + srow) * NN + kbase + kg;

  f4_t ra = *(const f4_t*)lrow;
  f4_t rb = *(const f4_t*)(lrow + 4);
  {
    BFU ph, pl;
    #pragma unroll
    for (int c = 0; c < 8; ++c) {
      const float f = (c < 4) ? ra[c] : rb[c - 4];
      const unsigned short hh = f2bf(f);
      ph.u[c] = hh;
      pl.u[c] = f2bf(f - bf2f(hh));
    }
    *(bf8v*)(ahb[0] + soff) = ph.v;
    *(bf8v*)(alb[0] + soff) = pl.v;
  }

  for (int tt = 0; tt < 16; ++tt) {
    const int cur = tt & 1;
    f4_t na, nb;
    if (tt < 15) {
      na = *(const f4_t*)(lrow + (tt + 1) * 128);
      nb = *(const f4_t*)(lrow + (tt + 1) * 128 + 4);
    }
    __syncthreads();
    #pragma unroll
    for (int si = 0; si < 4; ++si) {
      const int s = par * 4 + si;
      const int ra16 = (s * 64 + (lane ^ s)) * 16;
      const bf8v ah = *(const bf8v*)(ahb[cur] + ra16);
      const bf8v al = *(const bf8v*)(alb[cur] + ra16);
      const size_t bo = (size_t)((kbase >> 4) + tt * 8 + s) * 2048 + n * 512 + lane * 8;
      const bf8v bh = *(const bf8v*)(xfh + bo);
      const bf8v bl = *(const bf8v*)(xfl + bo);
      acc = __builtin_amdgcn_mfma_f32_32x32x16_bf16(ah, bh, acc, 0, 0, 0);
      acc = __builtin_amdgcn_mfma_f32_32x32x16_bf16(al, bh, acc, 0, 0, 0);
      acc = __builtin_amdgcn_mfma_f32_32x32x16_bf16(ah, bl, acc, 0, 0, 0);
    }
    if (tt < 15) {
      BFU ph, pl;
      #pragma unroll
      for (int c = 0; c < 8; ++c) {
        const float f = (c < 4) ? na[c] : nb[c - 4];
        const unsigned short hh = f2bf(f);
        ph.u[c] = hh;
        pl.u[c] = f2bf(f - bf2f(hh));
      }
      *(bf8v*)(ahb[cur ^ 1] + soff) = ph.v;
      *(bf8v*)(alb[cur ^ 1] + soff) = pl.v;
    }
  }

  // parity reduction via LDS (reuse ahb: 16 KB = red[4][32][32])
  float* red = (float*)&ahb[0][0];
  __syncthreads();
  const int la = lane & 31;
  if (par == 1) {
    #pragma unroll
    for (int reg = 0; reg < 16; ++reg) {
      const int row = (reg & 3) + 8*(reg >> 2) + 4*(lane >> 5);
      red[n*1024 + row*32 + la] = acc[reg];
    }
  }
  __syncthreads();
  if (par == 0) {
    #pragma unroll
    for (int reg = 0; reg < 16; ++reg) {
      const int row = (reg & 3) + 8*(reg >> 2) + 4*(lane >> 5);
      out[(size_t)(r0 + row) * 128 + n*32 + la] = acc[reg] + red[n*1024 + row*32 + la];
    }
  }
}

// ---------------------------------------------------------------------------
// U-GEMMs: U = x@W0 + (Hx_kz0 + Hx_kz1)@W1, emitted as bf16 hi/lo FRAGMENTS.
__global__ __launch_bounds__(256) void k_ugemm(
    const float* __restrict__ x, const float* __restrict__ Wi_w,
    const float* __restrict__ Ws_w, float* __restrict__ ws,
    const float* __restrict__ hx2,
    unsigned short* __restrict__ uih, unsigned short* __restrict__ uil,
    unsigned short* __restrict__ ush, unsigned short* __restrict__ usl) {
  const int rb = blockIdx.x;
  const int sel = blockIdx.y;
  const float* A[2]; const float* A2[2]; const float* W[2];
  unsigned short* uh; unsigned short* ul;
  if (sel == 0) { A[0]=x; A2[0]=nullptr; W[0]=Wi_w;
                  A[1]=ws+HXI_OFF; A2[1]=hx2; W[1]=Wi_w+16384; uh=uih; ul=uil; }
  else          { A[0]=x; A2[0]=nullptr; W[0]=Ws_w;
                  A[1]=ws+HXS_OFF; A2[1]=hx2+(size_t)NN*128; W[1]=Ws_w+16384; uh=ush; ul=usl; }

  __shared__ __align__(16) float At[32][33];
  __shared__ __align__(16) float Wt[32][144];
  const int t = threadIdx.x;
  const int rg = t >> 4, cg = t & 15;
  const int r0 = rb * 32;
  float acc[2][8];
  #pragma unroll
  for (int i = 0; i < 2; ++i)
    #pragma unroll
    for (int j = 0; j < 8; ++j) acc[i][j] = 0.f;

  for (int ps = 0; ps < 2; ++ps) {
    const float* __restrict__ Ap = A[ps];
    const float* __restrict__ Ap2 = A2[ps];
    const float* __restrict__ Wp = W[ps];
    for (int k0 = 0; k0 < 128; k0 += 32) {
      __syncthreads();
      {
        const int row = t >> 3, kq = t & 7;
        float4 av = *(const float4*)&Ap[(r0 + row)*128 + k0 + kq*4];
        if (Ap2) {
          const float4 av2 = *(const float4*)&Ap2[(r0 + row)*128 + k0 + kq*4];
          av.x += av2.x; av.y += av2.y; av.z += av2.z; av.w += av2.w;
        }
        At[row][kq*4+0] = av.x; At[row][kq*4+1] = av.y;
        At[row][kq*4+2] = av.z; At[row][kq*4+3] = av.w;
      }
      #pragma unroll
      for (int l = 0; l < 4; ++l) {
        const int idx = t + l*256;
        const int kr = idx >> 5, c4 = idx & 31;
        const float4 wv = *(const float4*)&Wp[(k0 + kr)*128 + c4*4];
        *(float4*)&Wt[kr][XI(c4*4)] = wv;
      }
      __syncthreads();
      #pragma unroll
      for (int k = 0; k < 32; ++k) {
        const float a0 = At[rg*2 + 0][k];
        const float a1 = At[rg*2 + 1][k];
        const float4 b0 = *(const float4*)&Wt[k][XI(cg*8)];
        const float4 b1 = *(const float4*)&Wt[k][XI(cg*8 + 4)];
        acc[0][0] += a0*b0.x; acc[0][1] += a0*b0.y; acc[0][2] += a0*b0.z; acc[0][3] += a0*b0.w;
        acc[0][4] += a0*b1.x; acc[0][5] += a0*b1.y; acc[0][6] += a0*b1.z; acc[0][7] += a0*b1.w;
        acc[1][0] += a1*b0.x; acc[1][1] += a1*b0.y; acc[1][2] += a1*b0.z; acc[1][3] += a1*b0.w;
        acc[1][4] += a1*b1.x; acc[1][5] += a1*b1.y; acc[1][6] += a1*b1.z; acc[1][7] += a1*b1.w;
      }
    }
  }
  #pragma unroll
  for (int i = 0; i < 2; ++i) {
    const int r = r0 + rg*2 + i;
    #pragma unroll
    for (int j = 0; j < 8; ++j) {
      const int c = cg*8 + j;
      const float val = acc[i][j];
      const unsigned short h = f2bf(val);
      const unsigned short l = f2bf(val - bf2f(h));
      const size_t fa = FRAG(c, r);
      uh[fa] = h;
      ul[fa] = l;
    }
  }
}

// ---------------------------------------------------------------------------
// Dense masked-softmax attention via MFMA, v5: NO ATOMICS, same structure as
// k_hxmm; E computed once/element during stage; per-row denominator via LDS.
// kz0 -> OI/OS; kz1 -> reuses HXI/HXS (dead after k_ugemm). den -> denp.
__global__ __launch_bounds__(512) void k_attnmm(
    const float* __restrict__ Ld, const float* __restrict__ Lu,
    float* __restrict__ ws, const unsigned short* __restrict__ uih,
    const unsigned short* __restrict__ uil, const unsigned short* __restrict__ ush,
    const unsigned short* __restrict__ usl, float* __restrict__ denp) {
  const int bid = blockIdx.x;
  const int br  = (bid >> 2) & 1;
  const int rest = ((bid >> 3) << 2) | (bid & 3);
  const int rblk = rest & 127;
  const int kz   = rest >> 7;
  const int t = threadIdx.x;
  const int lane = t & 63;
  const int n = (t >> 6) & 3, par = t >> 8;
  const int r0 = rblk * 32;
  const int kbase = kz * 2048;
  const float* __restrict__ L = br ? Lu : Ld;
  const unsigned short* __restrict__ ufh = br ? ush : uih;
  const unsigned short* __restrict__ ufl = br ? usl : uil;
  float* __restrict__ out = kz ? (ws + (br ? HXS_OFF : HXI_OFF))
                               : (ws + (br ? OS_OFF : OI_OFF));
  float* __restrict__ dout = denp + (size_t)(kz * 2 + br) * NN;
  const float* __restrict__ s1b = ws + S_OFF + (br ? 2*NN : 0) + r0;
  const float* __restrict__ s2b = ws + S_OFF + (br ? 3*NN : NN) + kbase;

  __shared__ __align__(16) char ahb[2][8192];
  __shared__ __align__(16) char alb[2][8192];
  __shared__ float dend[32][16];

  f32x16 acc;
  #pragma unroll
  for (int e = 0; e < 16; ++e) acc[e] = 0.f;
  float dp = 0.f;

  const int srow = t >> 4;
  const int kg   = (t & 15) * 8;
  const int sS   = kg >> 4;
  const int lt   = srow + 32 * ((kg >> 3) & 1);
  const int soff = (sS * 64 + (lt ^ sS)) * 16;
  const float s1v = s1b[srow];

  const float* __restrict__ lrow = L + (size_t)(r0 + srow) * NN + kbase + kg;

  f4_t ra = *(const f4_t*)lrow;
  f4_t rb = *(const f4_t*)(lrow + 4);
  {
    const f4_t s2a = *(const f4_t*)(s2b + kg);
    const f4_t s2c = *(const f4_t*)(s2b + kg + 4);
    BFU ph, pl;
    #pragma unroll
    for (int c = 0; c < 8; ++c) {
      const float Lv = (c < 4) ? ra[c] : rb[c - 4];
      const float s2 = (c < 4) ? s2a[c] : s2c[c - 4];
      const float sc = s1v + s2;
      const float scl = sc >= 0.f ? sc : SLOPE * sc;
      const float ex = (Lv != 0.f) ? __expf(scl) : 0.f;
      dp += ex;
      const unsigned short hh = f2bf(ex);
      ph.u[c] = hh;
      pl.u[c] = f2bf(ex - bf2f(hh));
    }
    *(bf8v*)(ahb[0] + soff) = ph.v;
    *(bf8v*)(alb[0] + soff) = pl.v;
  }

  for (int tt = 0; tt < 16; ++tt) {
    const int cur = tt & 1;
    f4_t na, nb;
    if (tt < 15) {
      na = *(const f4_t*)(lrow + (tt + 1) * 128);
      nb = *(const f4_t*)(lrow + (tt + 1) * 128 + 4);
    }
    __syncthreads();
    #pragma unroll
    for (int si = 0; si < 4; ++si) {
      const int s = par * 4 + si;
      const int ra16 = (s * 64 + (lane ^ s)) * 16;
      const bf8v ah = *(const bf8v*)(ahb[cur] + ra16);
      const bf8v al = *(const bf8v*)(alb[cur] + ra16);
      const size_t bo = (size_t)((kbase >> 4) + tt * 8 + s) * 2048 + n * 512 + lane * 8;
      const bf8v bh = *(const bf8v*)(ufh + bo);
      const bf8v bl = *(const bf8v*)(ufl + bo);
      acc = __builtin_amdgcn_mfma_f32_32x32x16_bf16(ah, bh, acc, 0, 0, 0);
      acc = __builtin_amdgcn_mfma_f32_32x32x16_bf16(al, bh, acc, 0, 0, 0);
      acc = __builtin_amdgcn_mfma_f32_32x32x16_bf16(ah, bl, acc, 0, 0, 0);
    }
    if (tt < 15) {
      const f4_t s2a = *(const f4_t*)(s2b + (tt + 1) * 128 + kg);
      const f4_t s2c = *(const f4_t*)(s2b + (tt + 1) * 128 + kg + 4);
      BFU ph, pl;
      #pragma unroll
      for (int c = 0; c < 8; ++c) {
        const float Lv = (c < 4) ? na[c] : nb[c - 4];
        const float s2 = (c < 4) ? s2a[c] : s2c[c - 4];
        const float sc = s1v + s2;
        const float scl = sc >= 0.f ? sc : SLOPE * sc;
        const float ex = (Lv != 0.f) ? __expf(scl) : 0.f;
        dp += ex;
        const unsigned short hh = f2bf(ex);
        ph.u[c] = hh;
        pl.u[c] = f2bf(ex - bf2f(hh));
      }
      *(bf8v*)(ahb[cur ^ 1] + soff) = ph.v;
      *(bf8v*)(alb[cur ^ 1] + soff) = pl.v;
    }
  }

  dend[srow][t & 15] = dp;
  float* red = (float*)&ahb[0][0];
  __syncthreads();
  if (t < 32) {   // per-row denominator for this (kz,br) K-half
    float d = 0.f;
    #pragma unroll
    for (int i = 0; i < 16; ++i) d += dend[t][i];
    dout[r0 + t] = d;
  }
  const int la = lane & 31;
  if (par == 1) {
    #pragma unroll
    for (int reg = 0; reg < 16; ++reg) {
      const int row = (reg & 3) + 8*(reg >> 2) + 4*(lane >> 5);
      red[n*1024 + row*32 + la] = acc[reg];
    }
  }
  __syncthreads();
  if (par == 0) {
    #pragma unroll
    for (int reg = 0; reg < 16; ++reg) {
      const int row = (reg & 3) + 8*(reg >> 2) + 4*(lane >> 5);
      out[(size_t)(r0 + row) * 128 + n*32 + la] = acc[reg] + red[n*1024 + row*32 + la];
    }
  }
}

// ---------------------------------------------------------------------------
// Dense P @ xWh via MFMA (round-6 form, best measured): BM=32, grid (128,8),
// fragment-ordered B, nt A-loads with one-step prefetch.
__global__ __launch_bounds__(256) void k_pgemm(
    const float* __restrict__ P, const unsigned short* __restrict__ xth,
    const unsigned short* __restrict__ xtl, float* __restrict__ zpart) {
  const int t = threadIdx.x;
  const int w = t >> 6, lane = t & 63;
  const int la = lane & 31;
  const int koff = (lane >> 5) * 8;
  const int r0 = blockIdx.x * 32;
  const int kz = blockIdx.y;
  const int kb = kz * 512 + w * 128;

  f32x16 acc[4];
  #pragma unroll
  for (int n = 0; n < 4; ++n)
    #pragma unroll
    for (int e = 0; e < 16; ++e) acc[n][e] = 0.f;

  const float* __restrict__ arow = P + (size_t)(r0 + la) * NN + kb + koff;
  const unsigned short* __restrict__ bh_base = xth + (size_t)kb * 128 + lane * 8;
  const unsigned short* __restrict__ bl_base = xtl + (size_t)kb * 128 + lane * 8;

  f4_t a0 = __builtin_nontemporal_load((const f4_t*)arow);
  f4_t a1 = __builtin_nontemporal_load((const f4_t*)(arow + 4));
  for (int s = 0; s < 8; ++s) {
    f4_t na0 = a0, na1 = a1;
    if (s < 7) {
      na0 = __builtin_nontemporal_load((const f4_t*)(arow + (s + 1) * 16));
      na1 = __builtin_nontemporal_load((const f4_t*)(arow + (s + 1) * 16 + 4));
    }
    BFU ah, al;
    #pragma unroll
    for (int i = 0; i < 8; ++i) {
      const float f = (i < 4) ? a0[i] : a1[i - 4];
      const unsigned short h = f2bf(f);
      ah.u[i] = h;
      al.u[i] = f2bf(f - bf2f(h));
    }
    const unsigned short* __restrict__ bh_s = bh_base + s * 2048;
    const unsigned short* __restrict__ bl_s = bl_base + s * 2048;
    #pragma unroll
    for (int n = 0; n < 4; ++n) {
      const bf8v bh = *(const bf8v*)(bh_s + n * 512);
      const bf8v bl = *(const bf8v*)(bl_s + n * 512);
      acc[n] = __builtin_amdgcn_mfma_f32_32x32x16_bf16(ah.v, bh, acc[n], 0, 0, 0);
      acc[n] = __builtin_amdgcn_mfma_f32_32x32x16_bf16(al.v, bh, acc[n], 0, 0, 0);
      acc[n] = __builtin_amdgcn_mfma_f32_32x32x16_bf16(ah.v, bl, acc[n], 0, 0, 0);
    }
    a0 = na0; a1 = na1;
  }

  __shared__ float red[2][32][128];
  if (w < 2) {
    #pragma unroll
    for (int n = 0; n < 4; ++n)
      #pragma unroll
      for (int reg = 0; reg < 16; ++reg) {
        const int row = (reg & 3) + 8*(reg >> 2) + 4*(lane >> 5);
        red[w][row][32*n + la] = acc[n][reg];
      }
  }
  __syncthreads();
  if (w >= 2) {
    #pragma unroll
    for (int n = 0; n < 4; ++n)
      #pragma unroll
      for (int reg = 0; reg < 16; ++reg) {
        const int row = (reg & 3) + 8*(reg >> 2) + 4*(lane >> 5);
        red[w - 2][row][32*n + la] += acc[n][reg];
      }
  }
  __syncthreads();
  float* __restrict__ zp = zpart + (size_t)kz * NN * 128;
  #pragma unroll
  for (int i = 0; i < 8; ++i) {
    const int row = w * 8 + i;
    zp[(size_t)(r0 + row) * 128 + lane]      = red[0][row][lane]      + red[1][row][lane];
    zp[(size_t)(r0 + row) * 128 + 64 + lane] = red[0][row][64 + lane] + red[1][row][64 + lane];
  }
}

// ---------------------------------------------------------------------------
// z = (Oi0+Oi1)/di + (Os0+Os1)/ds + sum_k zpart[k] + b_total
// (kz1 attn partials live in the reused HXI/HXS buffers)
__global__ __launch_bounds__(256) void k_combine(const float* __restrict__ ws,
                                                 const float* __restrict__ denp,
                                                 float* __restrict__ z) {
  const int i = blockIdx.x * 256 + threadIdx.x;
  const int col = i & 127;
  const int row = i >> 7;
  const float di = denp[row] + denp[2*NN + row];
  const float ds = denp[NN + row] + denp[3*NN + row];
  const float oi = ws[OI_OFF + i] + ws[HXI_OFF + i];
  const float os = ws[OS_OFF + i] + ws[HXS_OFF + i];
  float acc = ws[BT_OFF + col] + oi / di + os / ds;
  #pragma unroll
  for (int kz = 0; kz < 8; ++kz) acc += ws[ZP_OFF + kz*NN*128 + i];
  z[i] = acc;
}

// ---------------------------------------------------------------------------
extern "C" void kernel_launch(void* const* d_in, const int* in_sizes, int n_in,
                              void* d_out, int out_size, void* d_ws, size_t ws_size,
                              hipStream_t stream) {
  const float* x       = (const float*)d_in[0];
  const float* Lu      = (const float*)d_in[1];
  const float* Ld      = (const float*)d_in[2];
  const float* P       = (const float*)d_in[3];
  const float* Wi_w    = (const float*)d_in[4];
  const float* Wi_b    = (const float*)d_in[5];
  const float* Ws_w    = (const float*)d_in[6];
  const float* Ws_b    = (const float*)d_in[7];
  const float* Wh_w    = (const float*)d_in[8];
  const float* Wh_b    = (const float*)d_in[9];
  const float* att_irr = (const float*)d_in[10];
  const float* att_sol = (const float*)d_in[11];
  float* z  = (float*)d_out;
  float* ws = (float*)d_ws;
  float*          zpart = ws + ZP_OFF;
  unsigned short* xth   = (unsigned short*)(ws + XWH_OFF);
  unsigned short* xtl   = xth + (size_t)128 * NN;
  unsigned short* uih   = (unsigned short*)(ws + UI_OFF);
  unsigned short* uil   = uih + (size_t)128 * NN;
  unsigned short* ush   = (unsigned short*)(ws + US_OFF);
  unsigned short* usl   = ush + (size_t)128 * NN;
  unsigned short* xfh   = (unsigned short*)((char*)d_ws + XF_BYTE_OFF);
  unsigned short* xfl   = xfh + (size_t)128 * NN;
  float*          hx2   = (float*)((char*)d_ws + HX2_BYTE_OFF);
  float*          denp  = (float*)((char*)d_ws + DEN_BYTE_OFF);

  k_prep<<<1, 128, 0, stream>>>(Wi_w, Wi_b, Ws_w, Ws_b, Wh_b, att_irr, att_sol, ws);
  k_pre2<<<1152, 256, 0, stream>>>(x, Wh_w, ws, xth, xtl, xfh, xfl);
  k_hxmm<<<512, 512, 0, stream>>>(Ld, Lu, xfh, xfl, ws, hx2);
  {
    dim3 g(128, 2);
    k_ugemm<<<g, 256, 0, stream>>>(x, Wi_w, Ws_w, ws, hx2, uih, uil, ush, usl);
  }
  k_attnmm<<<512, 512, 0, stream>>>(Ld, Lu, ws, uih, uil, ush, usl, denp);
  {
    dim3 g(128, 8);
    k_pgemm<<<g, 256, 0, stream>>>(P, xth, xtl, zpart);
  }
  k_combine<<<NN * 128 / 256, 256, 0, stream>>>(ws, denp, z);
}